// Round 1
// baseline (991.995 us; speedup 1.0000x reference)
//
#include <hip/hip_runtime.h>
#include <hip/hip_bf16.h>

// Problem constants
#define BATCH 4
#define SEQ   1024
#define NHEAD 16
#define DHEAD 64
#define DMODEL 1024
#define NROWS (BATCH*SEQ)        // 4096
#define BH    (BATCH*NHEAD)      // 64
#define CLIPV 0.999999f          // 1 - 1e-6

// score = (1 + acos(clip(dot)))^(-65)
__device__ __forceinline__ float spfns_score(float dot) {
    dot = fminf(fmaxf(dot, -CLIPV), CLIPV);
    float g = acosf(dot);
    return exp2f(-65.0f * log2f(1.0f + g));
}

// ---------------------------------------------------------------------------
// K1/K5: C = X @ W + bias.  X: [NROWS x 1024] row-major, W: [1024 x 1024].
// headMajor=1: write to [b][h][s][dh] layout; else row-major [n][d].
// 64x64 tile, 256 threads, 4x4 micro-tile, both operands read as float4 from
// transposed/row LDS tiles.
// ---------------------------------------------------------------------------
__global__ __launch_bounds__(256) void gemm64(const float* __restrict__ X,
                                              const float* __restrict__ W,
                                              const float* __restrict__ bias,
                                              float* __restrict__ outp,
                                              int headMajor)
{
    __shared__ float Ast[16][68];   // [k][n] transposed
    __shared__ float Bs[16][68];    // [k][d]
    const int n0 = blockIdx.x * 64;
    const int d0 = blockIdx.y * 64;
    const int t  = threadIdx.x;
    const int tx = t & 15, ty = t >> 4;

    float acc[4][4] = {};

    for (int k0 = 0; k0 < 1024; k0 += 16) {
        // stage A (transpose): thread loads float4 of 4 consecutive k for one n
        {
            int n  = t >> 2;
            int k4 = (t & 3) * 4;
            float4 xv = *reinterpret_cast<const float4*>(&X[(n0 + n) * 1024 + k0 + k4]);
            Ast[k4 + 0][n] = xv.x;
            Ast[k4 + 1][n] = xv.y;
            Ast[k4 + 2][n] = xv.z;
            Ast[k4 + 3][n] = xv.w;
            // stage B row-major
            int kr = t >> 4;
            int d4 = (t & 15) * 4;
            float4 wv = *reinterpret_cast<const float4*>(&W[(k0 + kr) * 1024 + d0 + d4]);
            *reinterpret_cast<float4*>(&Bs[kr][d4]) = wv;
        }
        __syncthreads();
        #pragma unroll
        for (int kk = 0; kk < 16; ++kk) {
            float4 a4 = *reinterpret_cast<const float4*>(&Ast[kk][ty * 4]);
            float4 b4 = *reinterpret_cast<const float4*>(&Bs[kk][tx * 4]);
            float av[4] = {a4.x, a4.y, a4.z, a4.w};
            float bv[4] = {b4.x, b4.y, b4.z, b4.w};
            #pragma unroll
            for (int ii = 0; ii < 4; ++ii)
                #pragma unroll
                for (int jj = 0; jj < 4; ++jj)
                    acc[ii][jj] += av[ii] * bv[jj];
        }
        __syncthreads();
    }

    // epilogue
    const int dbase = d0 + tx * 4;
    float4 b4 = *reinterpret_cast<const float4*>(&bias[dbase]);
    #pragma unroll
    for (int ii = 0; ii < 4; ++ii) {
        int n = n0 + ty * 4 + ii;
        float4 o;
        o.x = acc[ii][0] + b4.x;
        o.y = acc[ii][1] + b4.y;
        o.z = acc[ii][2] + b4.z;
        o.w = acc[ii][3] + b4.w;
        if (headMajor) {
            int b = n >> 10, s = n & 1023;
            int h = dbase >> 6, dh = dbase & 63;
            *reinterpret_cast<float4*>(&outp[(((b * NHEAD + h) * SEQ + s) * DHEAD) + dh]) = o;
        } else {
            *reinterpret_cast<float4*>(&outp[n * 1024 + dbase]) = o;
        }
    }
}

// ---------------------------------------------------------------------------
// K2: L2-normalize rows of 64 (q then k, contiguous). One wave per row.
// ---------------------------------------------------------------------------
__global__ __launch_bounds__(256) void l2norm_rows(float* __restrict__ buf)
{
    int row = blockIdx.x * 4 + (threadIdx.x >> 6);
    int l   = threadIdx.x & 63;
    float v = buf[row * 64 + l];
    float s = v * v;
    #pragma unroll
    for (int off = 32; off; off >>= 1) s += __shfl_xor(s, off);
    float scale = 1.0f / fmaxf(sqrtf(s), 1e-12f);
    buf[row * 64 + l] = v * scale;
}

// ---------------------------------------------------------------------------
// K3: column sums of the score matrix.  grid (bh, i-tile, j-tile).
// Transposed LDS tiles, 4x4 micro-tile dots, shuffle-reduce columns, atomicAdd.
// ---------------------------------------------------------------------------
__global__ __launch_bounds__(256) void colsum_kernel(const float* __restrict__ qn,
                                                     const float* __restrict__ kn,
                                                     float* __restrict__ nc)
{
    __shared__ float qT[64][68];   // [dh][i]
    __shared__ float kT[64][68];   // [dh][j]
    const int bh = blockIdx.x, i0 = blockIdx.y * 64, j0 = blockIdx.z * 64;
    const int t = threadIdx.x;

    const float* qb = qn + (bh * SEQ + i0) * DHEAD;
    const float* kb = kn + (bh * SEQ + j0) * DHEAD;
    for (int e = t; e < 1024; e += 256) {
        int r = e >> 4, c4 = (e & 15) * 4;
        float4 qv = *reinterpret_cast<const float4*>(&qb[r * 64 + c4]);
        qT[c4 + 0][r] = qv.x; qT[c4 + 1][r] = qv.y;
        qT[c4 + 2][r] = qv.z; qT[c4 + 3][r] = qv.w;
        float4 kv = *reinterpret_cast<const float4*>(&kb[r * 64 + c4]);
        kT[c4 + 0][r] = kv.x; kT[c4 + 1][r] = kv.y;
        kT[c4 + 2][r] = kv.z; kT[c4 + 3][r] = kv.w;
    }
    __syncthreads();

    const int ti = t & 15, tj = t >> 4;
    float dot[4][4] = {};
    #pragma unroll 8
    for (int dh = 0; dh < 64; ++dh) {
        float4 a4 = *reinterpret_cast<const float4*>(&qT[dh][ti * 4]);
        float4 b4 = *reinterpret_cast<const float4*>(&kT[dh][tj * 4]);
        float av[4] = {a4.x, a4.y, a4.z, a4.w};
        float bv[4] = {b4.x, b4.y, b4.z, b4.w};
        #pragma unroll
        for (int ii = 0; ii < 4; ++ii)
            #pragma unroll
            for (int jj = 0; jj < 4; ++jj)
                dot[ii][jj] += av[ii] * bv[jj];
    }

    float csum[4];
    #pragma unroll
    for (int jj = 0; jj < 4; ++jj) {
        float s = 0.f;
        #pragma unroll
        for (int ii = 0; ii < 4; ++ii) s += spfns_score(dot[ii][jj]);
        csum[jj] = s;
    }
    // reduce over ti (low 4 lane bits)
    #pragma unroll
    for (int off = 1; off < 16; off <<= 1) {
        #pragma unroll
        for (int jj = 0; jj < 4; ++jj) csum[jj] += __shfl_xor(csum[jj], off);
    }
    if (ti == 0) {
        #pragma unroll
        for (int jj = 0; jj < 4; ++jj)
            atomicAdd(&nc[bh * SEQ + j0 + tj * 4 + jj], csum[jj]);
    }
}

__global__ void rsqrt_kernel(float* __restrict__ nc)
{
    int i = blockIdx.x * 256 + threadIdx.x;
    if (i < BH * SEQ) nc[i] = rsqrtf(nc[i]);
}

// ---------------------------------------------------------------------------
// K4: pass B.  grid (bh, i-tile). Per 64-j chunk: recompute scores, scale by
// ncinv_j, stage wST[j][i] in LDS, micro-tiled PV; denominator accumulated
// from the already-loaded weight fragments (free).
// ---------------------------------------------------------------------------
__global__ __launch_bounds__(256) void attnpv_kernel(const float* __restrict__ qn,
                                                     const float* __restrict__ kn,
                                                     const float* __restrict__ vv,
                                                     const float* __restrict__ ncinv,
                                                     float* __restrict__ ao)
{
    __shared__ float qT[64][68];   // [dh][i]
    __shared__ float kT[64][68];   // [dh][j]
    __shared__ float vS[64][68];   // [j][dh]
    __shared__ float wS[64][68];   // [j][i]
    __shared__ float nciS[64];

    const int bh = blockIdx.x, i0 = blockIdx.y * 64;
    const int t = threadIdx.x;
    const int ti = t & 15, tj = t >> 4;

    // load q tile (transposed) once
    const float* qb = qn + (bh * SEQ + i0) * DHEAD;
    for (int e = t; e < 1024; e += 256) {
        int r = e >> 4, c4 = (e & 15) * 4;
        float4 qv = *reinterpret_cast<const float4*>(&qb[r * 64 + c4]);
        qT[c4 + 0][r] = qv.x; qT[c4 + 1][r] = qv.y;
        qT[c4 + 2][r] = qv.z; qT[c4 + 3][r] = qv.w;
    }

    float acc[4][4] = {};   // [ii][dd]
    float dacc[4]   = {};   // denom per ii

    for (int jc = 0; jc < 16; ++jc) {
        const int j0 = jc * 64;
        __syncthreads();   // prev phase2 reads done (also covers qT at jc=0)
        const float* kb = kn + (bh * SEQ + j0) * DHEAD;
        const float* vb = vv + (bh * SEQ + j0) * DHEAD;
        for (int e = t; e < 1024; e += 256) {
            int r = e >> 4, c4 = (e & 15) * 4;
            float4 kv = *reinterpret_cast<const float4*>(&kb[r * 64 + c4]);
            kT[c4 + 0][r] = kv.x; kT[c4 + 1][r] = kv.y;
            kT[c4 + 2][r] = kv.z; kT[c4 + 3][r] = kv.w;
            float4 v4 = *reinterpret_cast<const float4*>(&vb[r * 64 + c4]);
            *reinterpret_cast<float4*>(&vS[r][c4]) = v4;
        }
        if (t < 64) nciS[t] = ncinv[bh * SEQ + j0 + t];
        __syncthreads();

        // phase 1: scores for (i = 4*ti+ii, j = 4*tj+jj)
        float dot[4][4] = {};
        #pragma unroll 8
        for (int dh = 0; dh < 64; ++dh) {
            float4 a4 = *reinterpret_cast<const float4*>(&qT[dh][ti * 4]);
            float4 b4 = *reinterpret_cast<const float4*>(&kT[dh][tj * 4]);
            float av[4] = {a4.x, a4.y, a4.z, a4.w};
            float bv[4] = {b4.x, b4.y, b4.z, b4.w};
            #pragma unroll
            for (int ii = 0; ii < 4; ++ii)
                #pragma unroll
                for (int jj = 0; jj < 4; ++jj)
                    dot[ii][jj] += av[ii] * bv[jj];
        }
        #pragma unroll
        for (int jj = 0; jj < 4; ++jj) {
            float nci = nciS[tj * 4 + jj];
            float w4[4];
            #pragma unroll
            for (int ii = 0; ii < 4; ++ii)
                w4[ii] = spfns_score(dot[ii][jj]) * nci;
            float4 wv4 = {w4[0], w4[1], w4[2], w4[3]};
            *reinterpret_cast<float4*>(&wS[tj * 4 + jj][ti * 4]) = wv4;
        }
        __syncthreads();

        // phase 2: PV micro-GEMM. thread owns i = 4*ti+ii, dh = 4*tj+dd
        #pragma unroll 8
        for (int j = 0; j < 64; ++j) {
            float4 a4 = *reinterpret_cast<const float4*>(&wS[j][ti * 4]);
            float4 b4 = *reinterpret_cast<const float4*>(&vS[j][tj * 4]);
            float av[4] = {a4.x, a4.y, a4.z, a4.w};
            float bv[4] = {b4.x, b4.y, b4.z, b4.w};
            #pragma unroll
            for (int ii = 0; ii < 4; ++ii) {
                dacc[ii] += av[ii];
                #pragma unroll
                for (int dd = 0; dd < 4; ++dd)
                    acc[ii][dd] += av[ii] * bv[dd];
            }
        }
    }

    // dacc counted each j exactly once per chunk, but every thread with the
    // same ti accumulated the identical sum -> no reduction needed.
    // NOTE: dacc was accumulated once per (ii, j) -- correct: denom_i = sum_j w[i][j].
    const int b = bh >> 4, h = bh & 15;
    #pragma unroll
    for (int ii = 0; ii < 4; ++ii) {
        int n = b * SEQ + i0 + ti * 4 + ii;
        float inv = 1.0f / dacc[ii];
        float4 o;
        o.x = acc[ii][0] * inv;
        o.y = acc[ii][1] * inv;
        o.z = acc[ii][2] * inv;
        o.w = acc[ii][3] * inv;
        *reinterpret_cast<float4*>(&ao[n * DMODEL + h * DHEAD + tj * 4]) = o;
    }
}

// ---------------------------------------------------------------------------
extern "C" void kernel_launch(void* const* d_in, const int* in_sizes, int n_in,
                              void* d_out, int out_size, void* d_ws, size_t ws_size,
                              hipStream_t stream)
{
    (void)in_sizes; (void)n_in; (void)out_size; (void)ws_size;
    const float* x  = (const float*)d_in[0];
    const float* wq = (const float*)d_in[1];
    const float* bq = (const float*)d_in[2];
    const float* wk = (const float*)d_in[3];
    const float* bk = (const float*)d_in[4];
    const float* wv = (const float*)d_in[5];
    const float* bv = (const float*)d_in[6];
    const float* wo = (const float*)d_in[7];
    const float* bo = (const float*)d_in[8];
    float* out = (float*)d_out;

    float* ws = (float*)d_ws;
    const size_t HEADMAT = (size_t)BH * SEQ * DHEAD;   // 4,194,304 floats
    float* qn = ws;
    float* kn = qn + HEADMAT;
    float* vh = kn + HEADMAT;
    float* ao = vh + HEADMAT;                          // [n][d] row-major
    float* nc = ao + (size_t)NROWS * DMODEL;           // 65,536 floats

    dim3 gg(NROWS / 64, DMODEL / 64);                  // (64,16)
    gemm64<<<gg, 256, 0, stream>>>(x, wq, bq, qn, 1);
    gemm64<<<gg, 256, 0, stream>>>(x, wk, bk, kn, 1);
    gemm64<<<gg, 256, 0, stream>>>(x, wv, bv, vh, 1);

    // normalize q and k rows (contiguous buffers: 2*BH*SEQ rows of 64)
    l2norm_rows<<<(2 * BH * SEQ) / 4, 256, 0, stream>>>(qn);

    hipMemsetAsync(nc, 0, BH * SEQ * sizeof(float), stream);
    colsum_kernel<<<dim3(BH, SEQ / 64, SEQ / 64), 256, 0, stream>>>(qn, kn, nc);
    rsqrt_kernel<<<(BH * SEQ) / 256, 256, 0, stream>>>(nc);

    attnpv_kernel<<<dim3(BH, SEQ / 64), 256, 0, stream>>>(qn, kn, vh, nc, ao);

    gemm64<<<gg, 256, 0, stream>>>(ao, wo, bo, out, 0);
}

// Round 2
// 293.907 us; speedup vs baseline: 3.3752x; 3.3752x over previous
//
#include <hip/hip_runtime.h>
#include <hip/hip_bf16.h>
#include <cstdint>
#include <cstddef>

// ---------------- problem constants ----------------
#define BATCH  4
#define SEQ    1024
#define NHEAD  16
#define DHEAD  64
#define DMODEL 1024
#define NROWS  4096          // BATCH*SEQ
#define BH     64            // BATCH*NHEAD
#define CLIPV  0.999999f
#define PEXP   65.0f         // d_intrinsic + alpha

typedef _Float16 h16;
typedef _Float16 half8 __attribute__((ext_vector_type(8)));
typedef _Float16 half4 __attribute__((ext_vector_type(4)));
typedef float    f32x4 __attribute__((ext_vector_type(4)));

// t2 = log2(score) = -65*log2(1 + acos(clip(d)))
// acos via AS 4.4.46 minimax (|err|<=2e-8): acos(a)=sqrt(1-a)*p7(a), a in [0,1]
__device__ __forceinline__ float spfns_t2(float d) {
    d = fminf(fmaxf(d, -CLIPV), CLIPV);
    float a = fabsf(d);
    float s = sqrtf(1.0f - a);
    float p = -0.0012624911f;
    p = fmaf(p, a,  0.0066700901f);
    p = fmaf(p, a, -0.0170881256f);
    p = fmaf(p, a,  0.0308918810f);
    p = fmaf(p, a, -0.0501743046f);
    p = fmaf(p, a,  0.0889789874f);
    p = fmaf(p, a, -0.2145988016f);
    p = fmaf(p, a,  1.5707963050f);
    float r = s * p;
    float g = (d >= 0.0f) ? r : (3.14159265358979f - r);
    return -PEXP * log2f(1.0f + g);
}

// ---------------------------------------------------------------------------
// K1: x f32 -> xh f16
// ---------------------------------------------------------------------------
__global__ __launch_bounds__(256) void cvt_x(const float* __restrict__ x,
                                             h16* __restrict__ xh)
{
    size_t i = ((size_t)blockIdx.x * 256 + threadIdx.x) * 8;
    float4 a = *reinterpret_cast<const float4*>(&x[i]);
    float4 b = *reinterpret_cast<const float4*>(&x[i + 4]);
    half8 o;
    o[0]=(h16)a.x; o[1]=(h16)a.y; o[2]=(h16)a.z; o[3]=(h16)a.w;
    o[4]=(h16)b.x; o[5]=(h16)b.y; o[6]=(h16)b.z; o[7]=(h16)b.w;
    *reinterpret_cast<half8*>(&xh[i]) = o;
}

// ---------------------------------------------------------------------------
// K2: transpose+convert W [k][d] f32 -> Wt [d][k] f16.  z selects matrix.
// ---------------------------------------------------------------------------
__global__ __launch_bounds__(256) void wtrans(const float* __restrict__ wq,
                                              const float* __restrict__ wk,
                                              const float* __restrict__ wv,
                                              const float* __restrict__ wo,
                                              h16* __restrict__ wt3,
                                              h16* __restrict__ wot)
{
    __shared__ float T[64][65];
    const int k0 = blockIdx.x * 64, d0 = blockIdx.y * 64, z = blockIdx.z;
    const float* src = (z==0)?wq:(z==1)?wk:(z==2)?wv:wo;
    h16* dst = (z==3) ? wot : (wt3 + (size_t)z * 1024 * 1024);
    const int t = threadIdx.x;

    #pragma unroll
    for (int p = 0; p < 4; ++p) {
        int k = (t >> 4) + p * 16;
        int c = (t & 15) * 4;
        float4 v = *reinterpret_cast<const float4*>(&src[(size_t)(k0 + k) * 1024 + d0 + c]);
        T[c + 0][k] = v.x; T[c + 1][k] = v.y; T[c + 2][k] = v.z; T[c + 3][k] = v.w;
    }
    __syncthreads();
    #pragma unroll
    for (int p = 0; p < 2; ++p) {
        int dl = (t >> 3) + p * 32;
        int c  = (t & 7) * 8;
        half8 o;
        #pragma unroll
        for (int e = 0; e < 8; ++e) o[e] = (h16)T[dl][c + e];
        *reinterpret_cast<half8*>(&dst[(size_t)(d0 + dl) * 1024 + k0 + c]) = o;
    }
}

// ---------------------------------------------------------------------------
// K3: C = A(f16) @ Bt(f16)^T + bias.  128x128 tile, BK=64, 4 waves (2x2).
// mode 0: d in [0,3072): q/k -> head-major f16, v -> transposed vt f16.
// mode 1: d in [0,1024): out f32 row-major.
// ---------------------------------------------------------------------------
__global__ __launch_bounds__(256) void gemm_f16(const h16* __restrict__ A,
                                                const h16* __restrict__ Bt,
                                                const float* __restrict__ b0,
                                                const float* __restrict__ b1,
                                                const float* __restrict__ b2,
                                                h16* __restrict__ oq,
                                                h16* __restrict__ ok,
                                                h16* __restrict__ ovt,
                                                float* __restrict__ of32,
                                                int mode)
{
    __shared__ __align__(16) h16 As[128][72];
    __shared__ __align__(16) h16 Bs[128][72];
    const int n0 = blockIdx.x * 128, d0 = blockIdx.y * 128;
    const int t = threadIdx.x, l = t & 63, w = t >> 6;
    const int wr = (w >> 1) * 64, wc = (w & 1) * 64;

    f32x4 acc[4][4];
    #pragma unroll
    for (int i = 0; i < 4; ++i)
        #pragma unroll
        for (int j = 0; j < 4; ++j) acc[i][j] = (f32x4){0.f,0.f,0.f,0.f};

    for (int k0 = 0; k0 < 1024; k0 += 64) {
        __syncthreads();
        #pragma unroll
        for (int p = 0; p < 4; ++p) {
            int r = (t >> 3) + p * 32, c = (t & 7) * 8;
            *reinterpret_cast<half8*>(&As[r][c]) =
                *reinterpret_cast<const half8*>(&A[(size_t)(n0 + r) * 1024 + k0 + c]);
            *reinterpret_cast<half8*>(&Bs[r][c]) =
                *reinterpret_cast<const half8*>(&Bt[(size_t)(d0 + r) * 1024 + k0 + c]);
        }
        __syncthreads();
        #pragma unroll
        for (int kk = 0; kk < 2; ++kk) {
            half8 a[4], b[4];
            #pragma unroll
            for (int fi = 0; fi < 4; ++fi)
                a[fi] = *reinterpret_cast<const half8*>(&As[wr + fi*16 + (l & 15)][((l >> 4) * 8) + kk * 32]);
            #pragma unroll
            for (int fj = 0; fj < 4; ++fj)
                b[fj] = *reinterpret_cast<const half8*>(&Bs[wc + fj*16 + (l & 15)][((l >> 4) * 8) + kk * 32]);
            #pragma unroll
            for (int fi = 0; fi < 4; ++fi)
                #pragma unroll
                for (int fj = 0; fj < 4; ++fj)
                    acc[fi][fj] = __builtin_amdgcn_mfma_f32_16x16x32_f16(a[fi], b[fj], acc[fi][fj], 0, 0, 0);
        }
    }

    // epilogue
    #pragma unroll
    for (int fi = 0; fi < 4; ++fi) {
        #pragma unroll
        for (int fj = 0; fj < 4; ++fj) {
            int d = d0 + wc + fj * 16 + (l & 15);
            int s0n = n0 + wr + fi * 16 + ((l >> 4) << 2);
            if (mode == 0) {
                int mat = d >> 10, d1 = d & 1023, h = d1 >> 6, dh = d1 & 63;
                const float* bp = (mat == 0) ? b0 : (mat == 1) ? b1 : b2;
                float bias = bp[d1];
                if (mat == 2) {
                    int b = s0n >> 10, s0 = s0n & 1023;
                    half4 o;
                    #pragma unroll
                    for (int rr = 0; rr < 4; ++rr) o[rr] = (h16)(acc[fi][fj][rr] + bias);
                    *reinterpret_cast<half4*>(&ovt[(((size_t)(b * NHEAD + h)) * DHEAD + dh) * SEQ + s0]) = o;
                } else {
                    h16* dst = (mat == 0) ? oq : ok;
                    #pragma unroll
                    for (int rr = 0; rr < 4; ++rr) {
                        int n = s0n + rr, b = n >> 10, s = n & 1023;
                        dst[(((size_t)(b * NHEAD + h)) * SEQ + s) * DHEAD + dh] = (h16)(acc[fi][fj][rr] + bias);
                    }
                }
            } else {
                float bias = b0[d];
                #pragma unroll
                for (int rr = 0; rr < 4; ++rr) {
                    int n = s0n + rr;
                    of32[(size_t)n * DMODEL + d] = acc[fi][fj][rr] + bias;
                }
            }
        }
    }
}

// ---------------------------------------------------------------------------
// K4: L2-normalize rows of 64 f16 (qh and kh are contiguous).
// ---------------------------------------------------------------------------
__global__ __launch_bounds__(256) void l2norm_f16(h16* __restrict__ buf)
{
    const int t = threadIdx.x;
    size_t row = (size_t)blockIdx.x * 16 + (t >> 4);
    int c = (t & 15) * 4;
    half4 v = *reinterpret_cast<const half4*>(&buf[row * 64 + c]);
    float f0 = (float)v[0], f1 = (float)v[1], f2 = (float)v[2], f3 = (float)v[3];
    float s = f0*f0 + f1*f1 + f2*f2 + f3*f3;
    #pragma unroll
    for (int off = 1; off < 16; off <<= 1) s += __shfl_xor(s, off);
    float sc = 1.0f / fmaxf(sqrtf(s), 1e-12f);
    half4 o;
    o[0] = (h16)(f0 * sc); o[1] = (h16)(f1 * sc); o[2] = (h16)(f2 * sc); o[3] = (h16)(f3 * sc);
    *reinterpret_cast<half4*>(&buf[row * 64 + c]) = o;
}

// ---------------------------------------------------------------------------
// K5 pass A: per (j-tile, bh): column sums nc[j] over all i (no atomics),
// row min of -t2 (atomicMin uint), integer-atomic sum of log2(nc).
// ---------------------------------------------------------------------------
__global__ __launch_bounds__(256) void passA(const h16* __restrict__ qh,
                                             const h16* __restrict__ kh,
                                             float* __restrict__ nc,
                                             unsigned* __restrict__ rm_u,
                                             int* __restrict__ gacc)
{
    __shared__ __align__(16) h16 Ks[64][72];
    __shared__ __align__(16) h16 Qs[64][72];
    __shared__ float red[4][64];
    const int jt = blockIdx.x, bh = blockIdx.y;
    const int j0 = jt * 64;
    const int t = threadIdx.x, l = t & 63, w = t >> 6;

    // stage K tile (rows j0..j0+63)
    #pragma unroll
    for (int p = 0; p < 2; ++p) {
        int r = (t >> 3) + p * 32, c = (t & 7) * 8;
        *reinterpret_cast<half8*>(&Ks[r][c]) =
            *reinterpret_cast<const half8*>(&kh[(((size_t)bh * SEQ) + j0 + r) * DHEAD + c]);
    }
    __syncthreads();

    half8 kfr[4][2];
    #pragma unroll
    for (int fj = 0; fj < 4; ++fj)
        #pragma unroll
        for (int kk = 0; kk < 2; ++kk)
            kfr[fj][kk] = *reinterpret_cast<const half8*>(&Ks[fj*16 + (l & 15)][((l >> 4) * 8) + kk * 32]);

    float ncacc[4] = {0.f, 0.f, 0.f, 0.f};

    for (int it = 0; it < 16; ++it) {
        __syncthreads();
        #pragma unroll
        for (int p = 0; p < 2; ++p) {
            int r = (t >> 3) + p * 32, c = (t & 7) * 8;
            *reinterpret_cast<half8*>(&Qs[r][c]) =
                *reinterpret_cast<const half8*>(&qh[(((size_t)bh * SEQ) + it*64 + r) * DHEAD + c]);
        }
        __syncthreads();

        half8 aq[2];
        #pragma unroll
        for (int kk = 0; kk < 2; ++kk)
            aq[kk] = *reinterpret_cast<const half8*>(&Qs[w*16 + (l & 15)][((l >> 4) * 8) + kk * 32]);

        float mm[4] = {1e30f, 1e30f, 1e30f, 1e30f};
        #pragma unroll
        for (int fj = 0; fj < 4; ++fj) {
            f32x4 cfr = (f32x4){0.f,0.f,0.f,0.f};
            cfr = __builtin_amdgcn_mfma_f32_16x16x32_f16(aq[0], kfr[fj][0], cfr, 0, 0, 0);
            cfr = __builtin_amdgcn_mfma_f32_16x16x32_f16(aq[1], kfr[fj][1], cfr, 0, 0, 0);
            #pragma unroll
            for (int rr = 0; rr < 4; ++rr) {
                float t2 = spfns_t2(cfr[rr]);
                ncacc[fj] += exp2f(t2);
                mm[rr] = fminf(mm[rr], -t2);
            }
        }
        // row max of t2 = -min(-t2): reduce min over the 16 j-lanes
        #pragma unroll
        for (int rr = 0; rr < 4; ++rr) {
            float m = mm[rr];
            #pragma unroll
            for (int off = 1; off < 16; off <<= 1) m = fminf(m, __shfl_xor(m, off));
            if ((l & 15) == 0) {
                int row = it * 64 + w * 16 + ((l >> 4) << 2) + rr;
                atomicMin(&rm_u[(size_t)bh * SEQ + row], __float_as_uint(m));
            }
        }
    }

    // column-sum cross reduction
    #pragma unroll
    for (int fj = 0; fj < 4; ++fj) {
        ncacc[fj] += __shfl_xor(ncacc[fj], 16);
        ncacc[fj] += __shfl_xor(ncacc[fj], 32);
    }
    if ((l & 63) < 16) {
        #pragma unroll
        for (int fj = 0; fj < 4; ++fj) red[w][fj * 16 + l] = ncacc[fj];
    }
    __syncthreads();
    if (t < 64) {
        float v = red[0][t] + red[1][t] + red[2][t] + red[3][t];
        nc[(size_t)bh * SEQ + j0 + t] = v;
        atomicAdd(gacc, (int)rintf(log2f(v) * 64.0f));
    }
}

// ---------------------------------------------------------------------------
// K6: ncr = ncinv / geomean(ncinv) (power-of-2-free exact shift), lrm = max t2.
// ---------------------------------------------------------------------------
__global__ __launch_bounds__(256) void ncprep(const float* __restrict__ nc,
                                              const unsigned* __restrict__ rm_u,
                                              const int* __restrict__ gacc,
                                              float* __restrict__ ncr,
                                              float* __restrict__ lrm)
{
    int i = blockIdx.x * 256 + threadIdx.x;
    float Lm = (float)(*gacc) / (65536.0f * 64.0f);   // mean log2(nc)
    ncr[i] = exp2f(-0.5f * (log2f(nc[i]) - Lm));
    lrm[i] = -__uint_as_float(rm_u[i]);
}

// ---------------------------------------------------------------------------
// K7 pass B: per (i-tile, bh): stream j-chunks; QK^T (MFMA) -> transform ->
// P' f16 (per-row log-shifted, col-scaled) -> PV (MFMA); denom in f32.
// ---------------------------------------------------------------------------
__global__ __launch_bounds__(256) void passB(const h16* __restrict__ qh,
                                             const h16* __restrict__ kh,
                                             const h16* __restrict__ vt,
                                             const float* __restrict__ ncr,
                                             const float* __restrict__ lrm,
                                             h16* __restrict__ aoh)
{
    __shared__ __align__(16) h16 Qs[64][72];
    __shared__ __align__(16) h16 Ks[64][72];
    __shared__ __align__(16) h16 Vs[64][72];
    __shared__ __align__(16) h16 Ps[4][16][72];
    __shared__ float ncr_s[64];
    __shared__ float lrm_s[64];

    const int it = blockIdx.x, bh = blockIdx.y;
    const int i0 = it * 64;
    const int t = threadIdx.x, l = t & 63, w = t >> 6;

    // stage Q tile + lrm once
    #pragma unroll
    for (int p = 0; p < 2; ++p) {
        int r = (t >> 3) + p * 32, c = (t & 7) * 8;
        *reinterpret_cast<half8*>(&Qs[r][c]) =
            *reinterpret_cast<const half8*>(&qh[(((size_t)bh * SEQ) + i0 + r) * DHEAD + c]);
    }
    if (t < 64) lrm_s[t] = lrm[(size_t)bh * SEQ + i0 + t];
    __syncthreads();

    half8 aq[2];
    #pragma unroll
    for (int kk = 0; kk < 2; ++kk)
        aq[kk] = *reinterpret_cast<const half8*>(&Qs[w*16 + (l & 15)][((l >> 4) * 8) + kk * 32]);
    float lr[4];
    #pragma unroll
    for (int rr = 0; rr < 4; ++rr) lr[rr] = lrm_s[w*16 + ((l >> 4) << 2) + rr];

    f32x4 pv[4];
    #pragma unroll
    for (int fd = 0; fd < 4; ++fd) pv[fd] = (f32x4){0.f,0.f,0.f,0.f};
    float dsum[4] = {0.f, 0.f, 0.f, 0.f};

    for (int jc = 0; jc < 16; ++jc) {
        const int j0 = jc * 64;
        __syncthreads();   // previous chunk's PV reads complete
        #pragma unroll
        for (int p = 0; p < 2; ++p) {
            int r = (t >> 3) + p * 32, c = (t & 7) * 8;
            *reinterpret_cast<half8*>(&Ks[r][c]) =
                *reinterpret_cast<const half8*>(&kh[(((size_t)bh * SEQ) + j0 + r) * DHEAD + c]);
            *reinterpret_cast<half8*>(&Vs[r][c]) =
                *reinterpret_cast<const half8*>(&vt[(((size_t)bh * DHEAD) + r) * SEQ + j0 + c]);
        }
        if (t < 64) ncr_s[t] = ncr[(size_t)bh * SEQ + j0 + t];
        __syncthreads();

        // QK^T + transform -> Ps (per-wave slice)
        #pragma unroll
        for (int fj = 0; fj < 4; ++fj) {
            half8 kb0 = *reinterpret_cast<const half8*>(&Ks[fj*16 + (l & 15)][((l >> 4) * 8)]);
            half8 kb1 = *reinterpret_cast<const half8*>(&Ks[fj*16 + (l & 15)][((l >> 4) * 8) + 32]);
            f32x4 cfr = (f32x4){0.f,0.f,0.f,0.f};
            cfr = __builtin_amdgcn_mfma_f32_16x16x32_f16(aq[0], kb0, cfr, 0, 0, 0);
            cfr = __builtin_amdgcn_mfma_f32_16x16x32_f16(aq[1], kb1, cfr, 0, 0, 0);
            float nrc = ncr_s[fj * 16 + (l & 15)];
            #pragma unroll
            for (int rr = 0; rr < 4; ++rr) {
                float t2 = spfns_t2(cfr[rr]);
                float pp = exp2f(t2 - lr[rr]) * nrc;
                h16 ph = (h16)pp;
                dsum[rr] += (float)ph;
                Ps[w][((l >> 4) << 2) + rr][fj * 16 + (l & 15)] = ph;
            }
        }
        __syncthreads();   // Ps visible (wave-local, but keep it safe)

        // PV
        half8 pa0 = *reinterpret_cast<const half8*>(&Ps[w][l & 15][((l >> 4) * 8)]);
        half8 pa1 = *reinterpret_cast<const half8*>(&Ps[w][l & 15][((l >> 4) * 8) + 32]);
        #pragma unroll
        for (int fd = 0; fd < 4; ++fd) {
            half8 vb0 = *reinterpret_cast<const half8*>(&Vs[fd*16 + (l & 15)][((l >> 4) * 8)]);
            half8 vb1 = *reinterpret_cast<const half8*>(&Vs[fd*16 + (l & 15)][((l >> 4) * 8) + 32]);
            pv[fd] = __builtin_amdgcn_mfma_f32_16x16x32_f16(pa0, vb0, pv[fd], 0, 0, 0);
            pv[fd] = __builtin_amdgcn_mfma_f32_16x16x32_f16(pa1, vb1, pv[fd], 0, 0, 0);
        }
    }

    // denominators: sum over the 16 j-lanes
    #pragma unroll
    for (int rr = 0; rr < 4; ++rr) {
        #pragma unroll
        for (int off = 1; off < 16; off <<= 1) dsum[rr] += __shfl_xor(dsum[rr], off);
    }

    const int b = bh >> 4, h = bh & 15;
    #pragma unroll
    for (int rr = 0; rr < 4; ++rr) {
        float inv = 1.0f / dsum[rr];
        int s = i0 + w * 16 + ((l >> 4) << 2) + rr;
        #pragma unroll
        for (int fd = 0; fd < 4; ++fd) {
            aoh[((size_t)(b * SEQ + s)) * DMODEL + h * DHEAD + fd * 16 + (l & 15)] =
                (h16)(pv[fd][rr] * inv);
        }
    }
}

// ---------------------------------------------------------------------------
extern "C" void kernel_launch(void* const* d_in, const int* in_sizes, int n_in,
                              void* d_out, int out_size, void* d_ws, size_t ws_size,
                              hipStream_t stream)
{
    (void)in_sizes; (void)n_in; (void)out_size; (void)ws_size;
    const float* x  = (const float*)d_in[0];
    const float* wq = (const float*)d_in[1];
    const float* bq = (const float*)d_in[2];
    const float* wk = (const float*)d_in[3];
    const float* bk = (const float*)d_in[4];
    const float* wv = (const float*)d_in[5];
    const float* bv = (const float*)d_in[6];
    const float* wo = (const float*)d_in[7];
    const float* bo = (const float*)d_in[8];
    float* out = (float*)d_out;

    // workspace layout (halves first, then f32/u32)
    h16* ws16 = (h16*)d_ws;
    const size_t NX  = (size_t)NROWS * DMODEL;      // 4,194,304
    const size_t NW3 = (size_t)3 * DMODEL * DMODEL; // 3,145,728
    const size_t NW1 = (size_t)DMODEL * DMODEL;     // 1,048,576
    const size_t NH  = (size_t)BH * SEQ * DHEAD;    // 4,194,304
    h16* xh  = ws16;
    h16* wt3 = xh  + NX;
    h16* wot = wt3 + NW3;
    h16* qh  = wot + NW1;
    h16* kh  = qh  + NH;      // contiguous after qh (l2norm covers both)
    h16* vt  = kh  + NH;
    h16* aoh = vt  + NH;
    float* nc  = (float*)(aoh + NX);
    float* ncr = nc  + BH * SEQ;
    float* lrm = ncr + BH * SEQ;
    unsigned* rm_u = (unsigned*)(lrm + BH * SEQ);
    int* gacc = (int*)(rm_u + BH * SEQ);

    hipMemsetAsync(rm_u, 0xFF, (size_t)BH * SEQ * sizeof(unsigned), stream);
    hipMemsetAsync(gacc, 0, sizeof(int), stream);

    cvt_x<<<2048, 256, 0, stream>>>(x, xh);
    wtrans<<<dim3(16, 16, 4), 256, 0, stream>>>(wq, wk, wv, wo, wt3, wot);

    // q,k,v projections (d = 0..3071 over [wq|wk|wv])
    gemm_f16<<<dim3(32, 24), 256, 0, stream>>>(xh, wt3, bq, bk, bv,
                                               qh, kh, vt, nullptr, 0);
    l2norm_f16<<<(2 * BH * SEQ) / 16, 256, 0, stream>>>(qh);

    passA<<<dim3(16, BH), 256, 0, stream>>>(qh, kh, nc, rm_u, gacc);
    ncprep<<<256, 256, 0, stream>>>(nc, rm_u, gacc, ncr, lrm);
    passB<<<dim3(16, BH), 256, 0, stream>>>(qh, kh, vt, ncr, lrm, aoh);

    gemm_f16<<<dim3(32, 8), 256, 0, stream>>>(aoh, wot, bo, nullptr, nullptr,
                                              nullptr, nullptr, nullptr, out, 1);
}

// Round 3
// 227.855 us; speedup vs baseline: 4.3536x; 1.2899x over previous
//
#include <hip/hip_runtime.h>
#include <hip/hip_bf16.h>
#include <cstdint>
#include <cstddef>

// ---------------- problem constants ----------------
#define BATCH  4
#define SEQ    1024
#define NHEAD  16
#define DHEAD  64
#define DMODEL 1024
#define NROWS  4096          // BATCH*SEQ
#define BH     64            // BATCH*NHEAD
#define CLIPV  0.999999f
#define PEXP   65.0f         // d_intrinsic + alpha

typedef _Float16 h16;
typedef _Float16 half8 __attribute__((ext_vector_type(8)));
typedef _Float16 half4 __attribute__((ext_vector_type(4)));
typedef float    f32x4 __attribute__((ext_vector_type(4)));

// lg = log2(1 + acos(clip(d))).  score = 2^(-65*lg).
// acos via AS 4.4.46 minimax (|err|<=2e-8): acos(a)=sqrt(1-a)*p7(a), a in [0,1].
// All transcendentals are raw HW ops (v_sqrt/v_log: ~1ulp, fine vs 2e-2 tol).
__device__ __forceinline__ float spfns_lg(float d) {
    d = fminf(fmaxf(d, -CLIPV), CLIPV);
    float a = fabsf(d);
    float s = __builtin_amdgcn_sqrtf(1.0f - a);
    float p = -0.0012624911f;
    p = fmaf(p, a,  0.0066700901f);
    p = fmaf(p, a, -0.0170881256f);
    p = fmaf(p, a,  0.0308918810f);
    p = fmaf(p, a, -0.0501743046f);
    p = fmaf(p, a,  0.0889789874f);
    p = fmaf(p, a, -0.2145988016f);
    p = fmaf(p, a,  1.5707963050f);
    float r = s * p;
    float g = (d >= 0.0f) ? r : (3.14159265358979f - r);
    return __builtin_amdgcn_logf(1.0f + g);
}

// ---------------------------------------------------------------------------
// K1: x f32 -> xh f16
// ---------------------------------------------------------------------------
__global__ __launch_bounds__(256) void cvt_x(const float* __restrict__ x,
                                             h16* __restrict__ xh)
{
    size_t i = ((size_t)blockIdx.x * 256 + threadIdx.x) * 8;
    float4 a = *reinterpret_cast<const float4*>(&x[i]);
    float4 b = *reinterpret_cast<const float4*>(&x[i + 4]);
    half8 o;
    o[0]=(h16)a.x; o[1]=(h16)a.y; o[2]=(h16)a.z; o[3]=(h16)a.w;
    o[4]=(h16)b.x; o[5]=(h16)b.y; o[6]=(h16)b.z; o[7]=(h16)b.w;
    *reinterpret_cast<half8*>(&xh[i]) = o;
}

// ---------------------------------------------------------------------------
// K2: transpose+convert W [k][d] f32 -> Wt [d][k] f16.  z selects matrix.
// ---------------------------------------------------------------------------
__global__ __launch_bounds__(256) void wtrans(const float* __restrict__ wq,
                                              const float* __restrict__ wk,
                                              const float* __restrict__ wv,
                                              const float* __restrict__ wo,
                                              h16* __restrict__ wt3,
                                              h16* __restrict__ wot)
{
    __shared__ float T[64][65];
    const int k0 = blockIdx.x * 64, d0 = blockIdx.y * 64, z = blockIdx.z;
    const float* src = (z==0)?wq:(z==1)?wk:(z==2)?wv:wo;
    h16* dst = (z==3) ? wot : (wt3 + (size_t)z * 1024 * 1024);
    const int t = threadIdx.x;

    #pragma unroll
    for (int p = 0; p < 4; ++p) {
        int k = (t >> 4) + p * 16;
        int c = (t & 15) * 4;
        float4 v = *reinterpret_cast<const float4*>(&src[(size_t)(k0 + k) * 1024 + d0 + c]);
        T[c + 0][k] = v.x; T[c + 1][k] = v.y; T[c + 2][k] = v.z; T[c + 3][k] = v.w;
    }
    __syncthreads();
    #pragma unroll
    for (int p = 0; p < 2; ++p) {
        int dl = (t >> 3) + p * 32;
        int c  = (t & 7) * 8;
        half8 o;
        #pragma unroll
        for (int e = 0; e < 8; ++e) o[e] = (h16)T[dl][c + e];
        *reinterpret_cast<half8*>(&dst[(size_t)(d0 + dl) * 1024 + k0 + c]) = o;
    }
}

// ---------------------------------------------------------------------------
// K3: C = A(f16) @ Bt(f16)^T + bias.  128x128 tile, BK=64, 4 waves (2x2).
// mode 0: d in [0,3072): q/k -> head-major f16, v -> transposed vt f16.
// mode 1: d in [0,1024): out f32 row-major.
// ---------------------------------------------------------------------------
__global__ __launch_bounds__(256) void gemm_f16(const h16* __restrict__ A,
                                                const h16* __restrict__ Bt,
                                                const float* __restrict__ b0,
                                                const float* __restrict__ b1,
                                                const float* __restrict__ b2,
                                                h16* __restrict__ oq,
                                                h16* __restrict__ ok,
                                                h16* __restrict__ ovt,
                                                float* __restrict__ of32,
                                                int mode)
{
    __shared__ __align__(16) h16 As[128][72];
    __shared__ __align__(16) h16 Bs[128][72];
    const int n0 = blockIdx.x * 128, d0 = blockIdx.y * 128;
    const int t = threadIdx.x, l = t & 63, w = t >> 6;
    const int wr = (w >> 1) * 64, wc = (w & 1) * 64;

    f32x4 acc[4][4];
    #pragma unroll
    for (int i = 0; i < 4; ++i)
        #pragma unroll
        for (int j = 0; j < 4; ++j) acc[i][j] = (f32x4){0.f,0.f,0.f,0.f};

    for (int k0 = 0; k0 < 1024; k0 += 64) {
        __syncthreads();
        #pragma unroll
        for (int p = 0; p < 4; ++p) {
            int r = (t >> 3) + p * 32, c = (t & 7) * 8;
            *reinterpret_cast<half8*>(&As[r][c]) =
                *reinterpret_cast<const half8*>(&A[(size_t)(n0 + r) * 1024 + k0 + c]);
            *reinterpret_cast<half8*>(&Bs[r][c]) =
                *reinterpret_cast<const half8*>(&Bt[(size_t)(d0 + r) * 1024 + k0 + c]);
        }
        __syncthreads();
        #pragma unroll
        for (int kk = 0; kk < 2; ++kk) {
            half8 a[4], b[4];
            #pragma unroll
            for (int fi = 0; fi < 4; ++fi)
                a[fi] = *reinterpret_cast<const half8*>(&As[wr + fi*16 + (l & 15)][((l >> 4) * 8) + kk * 32]);
            #pragma unroll
            for (int fj = 0; fj < 4; ++fj)
                b[fj] = *reinterpret_cast<const half8*>(&Bs[wc + fj*16 + (l & 15)][((l >> 4) * 8) + kk * 32]);
            #pragma unroll
            for (int fi = 0; fi < 4; ++fi)
                #pragma unroll
                for (int fj = 0; fj < 4; ++fj)
                    acc[fi][fj] = __builtin_amdgcn_mfma_f32_16x16x32_f16(a[fi], b[fj], acc[fi][fj], 0, 0, 0);
        }
    }

    // epilogue
    #pragma unroll
    for (int fi = 0; fi < 4; ++fi) {
        #pragma unroll
        for (int fj = 0; fj < 4; ++fj) {
            int d = d0 + wc + fj * 16 + (l & 15);
            int s0n = n0 + wr + fi * 16 + ((l >> 4) << 2);
            if (mode == 0) {
                int mat = d >> 10, d1 = d & 1023, h = d1 >> 6, dh = d1 & 63;
                const float* bp = (mat == 0) ? b0 : (mat == 1) ? b1 : b2;
                float bias = bp[d1];
                if (mat == 2) {
                    int b = s0n >> 10, s0 = s0n & 1023;
                    half4 o;
                    #pragma unroll
                    for (int rr = 0; rr < 4; ++rr) o[rr] = (h16)(acc[fi][fj][rr] + bias);
                    *reinterpret_cast<half4*>(&ovt[(((size_t)(b * NHEAD + h)) * DHEAD + dh) * SEQ + s0]) = o;
                } else {
                    h16* dst = (mat == 0) ? oq : ok;
                    #pragma unroll
                    for (int rr = 0; rr < 4; ++rr) {
                        int n = s0n + rr, b = n >> 10, s = n & 1023;
                        dst[(((size_t)(b * NHEAD + h)) * SEQ + s) * DHEAD + dh] = (h16)(acc[fi][fj][rr] + bias);
                    }
                }
            } else {
                float bias = b0[d];
                #pragma unroll
                for (int rr = 0; rr < 4; ++rr) {
                    int n = s0n + rr;
                    of32[(size_t)n * DMODEL + d] = acc[fi][fj][rr] + bias;
                }
            }
        }
    }
}

// ---------------------------------------------------------------------------
// K4: L2-normalize rows of 64 f16 (qh and kh are contiguous).
// ---------------------------------------------------------------------------
__global__ __launch_bounds__(256) void l2norm_f16(h16* __restrict__ buf)
{
    const int t = threadIdx.x;
    size_t row = (size_t)blockIdx.x * 16 + (t >> 4);
    int c = (t & 15) * 4;
    half4 v = *reinterpret_cast<const half4*>(&buf[row * 64 + c]);
    float f0 = (float)v[0], f1 = (float)v[1], f2 = (float)v[2], f3 = (float)v[3];
    float s = f0*f0 + f1*f1 + f2*f2 + f3*f3;
    #pragma unroll
    for (int off = 1; off < 16; off <<= 1) s += __shfl_xor(s, off);
    float sc = __builtin_amdgcn_rcpf(fmaxf(__builtin_amdgcn_sqrtf(s), 1e-12f));
    half4 o;
    o[0] = (h16)(f0 * sc); o[1] = (h16)(f1 * sc); o[2] = (h16)(f2 * sc); o[3] = (h16)(f3 * sc);
    *reinterpret_cast<half4*>(&buf[row * 64 + c]) = o;
}

// ---------------------------------------------------------------------------
// K5 pass A: per (j-tile, bh): column sums nc[j] over all i (no atomics),
// row min of lg (atomicMin uint, lg > 0), integer-atomic sum of log2(nc).
// ---------------------------------------------------------------------------
__global__ __launch_bounds__(256) void passA(const h16* __restrict__ qh,
                                             const h16* __restrict__ kh,
                                             float* __restrict__ nc,
                                             unsigned* __restrict__ rm_u,
                                             int* __restrict__ gacc)
{
    __shared__ __align__(16) h16 Ks[64][72];
    __shared__ __align__(16) h16 Qs[64][72];
    __shared__ float red[4][64];
    const int jt = blockIdx.x, bh = blockIdx.y;
    const int j0 = jt * 64;
    const int t = threadIdx.x, l = t & 63, w = t >> 6;

    // stage K tile (rows j0..j0+63)
    #pragma unroll
    for (int p = 0; p < 2; ++p) {
        int r = (t >> 3) + p * 32, c = (t & 7) * 8;
        *reinterpret_cast<half8*>(&Ks[r][c]) =
            *reinterpret_cast<const half8*>(&kh[(((size_t)bh * SEQ) + j0 + r) * DHEAD + c]);
    }
    __syncthreads();

    half8 kfr[4][2];
    #pragma unroll
    for (int fj = 0; fj < 4; ++fj)
        #pragma unroll
        for (int kk = 0; kk < 2; ++kk)
            kfr[fj][kk] = *reinterpret_cast<const half8*>(&Ks[fj*16 + (l & 15)][((l >> 4) * 8) + kk * 32]);

    float ncacc[4] = {0.f, 0.f, 0.f, 0.f};

    for (int it = 0; it < 16; ++it) {
        __syncthreads();
        #pragma unroll
        for (int p = 0; p < 2; ++p) {
            int r = (t >> 3) + p * 32, c = (t & 7) * 8;
            *reinterpret_cast<half8*>(&Qs[r][c]) =
                *reinterpret_cast<const half8*>(&qh[(((size_t)bh * SEQ) + it*64 + r) * DHEAD + c]);
        }
        __syncthreads();

        half8 aq[2];
        #pragma unroll
        for (int kk = 0; kk < 2; ++kk)
            aq[kk] = *reinterpret_cast<const half8*>(&Qs[w*16 + (l & 15)][((l >> 4) * 8) + kk * 32]);

        float mm[4] = {1e30f, 1e30f, 1e30f, 1e30f};
        #pragma unroll
        for (int fj = 0; fj < 4; ++fj) {
            f32x4 cfr = (f32x4){0.f,0.f,0.f,0.f};
            cfr = __builtin_amdgcn_mfma_f32_16x16x32_f16(aq[0], kfr[fj][0], cfr, 0, 0, 0);
            cfr = __builtin_amdgcn_mfma_f32_16x16x32_f16(aq[1], kfr[fj][1], cfr, 0, 0, 0);
            #pragma unroll
            for (int rr = 0; rr < 4; ++rr) {
                float lg = spfns_lg(cfr[rr]);
                ncacc[fj] += __builtin_amdgcn_exp2f(-PEXP * lg);
                mm[rr] = fminf(mm[rr], lg);
            }
        }
        // row min of lg over the 16 j-lanes of each fragment row
        #pragma unroll
        for (int rr = 0; rr < 4; ++rr) {
            float m = mm[rr];
            #pragma unroll
            for (int off = 1; off < 16; off <<= 1) m = fminf(m, __shfl_xor(m, off));
            if ((l & 15) == 0) {
                int row = it * 64 + w * 16 + ((l >> 4) << 2) + rr;
                atomicMin(&rm_u[(size_t)bh * SEQ + row], __float_as_uint(m));
            }
        }
    }

    // column-sum cross reduction
    #pragma unroll
    for (int fj = 0; fj < 4; ++fj) {
        ncacc[fj] += __shfl_xor(ncacc[fj], 16);
        ncacc[fj] += __shfl_xor(ncacc[fj], 32);
    }
    if ((l & 63) < 16) {
        #pragma unroll
        for (int fj = 0; fj < 4; ++fj) red[w][fj * 16 + l] = ncacc[fj];
    }
    __syncthreads();
    if (t < 64) {
        float v = red[0][t] + red[1][t] + red[2][t] + red[3][t];
        nc[(size_t)bh * SEQ + j0 + t] = v;
        atomicAdd(gacc, (int)rintf(__builtin_amdgcn_logf(v) * 64.0f));
    }
}

// ---------------------------------------------------------------------------
// K6: lcr = log2 of geomean-normalized nc^-0.5;  lrm = row max of t2 = -65*min lg.
// ---------------------------------------------------------------------------
__global__ __launch_bounds__(256) void ncprep(const float* __restrict__ nc,
                                              const unsigned* __restrict__ rm_u,
                                              const int* __restrict__ gacc,
                                              float* __restrict__ lcr,
                                              float* __restrict__ lrm)
{
    int i = blockIdx.x * 256 + threadIdx.x;
    float Lm = (float)(*gacc) / (65536.0f * 64.0f);   // mean log2(nc)
    lcr[i] = -0.5f * (__builtin_amdgcn_logf(nc[i]) - Lm);
    lrm[i] = -PEXP * __uint_as_float(rm_u[i]);
}

// ---------------------------------------------------------------------------
// K7 pass B: per (i-tile, bh): stream j-chunks; QK^T (MFMA) ->
// p = exp2(fma(lg,-65, lcr_j - lrm_i)) -> P' f16 -> PV (MFMA); denom f32.
// ---------------------------------------------------------------------------
__global__ __launch_bounds__(256) void passB(const h16* __restrict__ qh,
                                             const h16* __restrict__ kh,
                                             const h16* __restrict__ vt,
                                             const float* __restrict__ lcr,
                                             const float* __restrict__ lrm,
                                             h16* __restrict__ aoh)
{
    __shared__ __align__(16) h16 Qs[64][72];
    __shared__ __align__(16) h16 Ks[64][72];
    __shared__ __align__(16) h16 Vs[64][72];
    __shared__ __align__(16) h16 Ps[4][16][72];
    __shared__ float lcr_s[64];
    __shared__ float lrm_s[64];

    const int it = blockIdx.x, bh = blockIdx.y;
    const int i0 = it * 64;
    const int t = threadIdx.x, l = t & 63, w = t >> 6;

    // stage Q tile + lrm once
    #pragma unroll
    for (int p = 0; p < 2; ++p) {
        int r = (t >> 3) + p * 32, c = (t & 7) * 8;
        *reinterpret_cast<half8*>(&Qs[r][c]) =
            *reinterpret_cast<const half8*>(&qh[(((size_t)bh * SEQ) + i0 + r) * DHEAD + c]);
    }
    if (t < 64) lrm_s[t] = lrm[(size_t)bh * SEQ + i0 + t];
    __syncthreads();

    half8 aq[2];
    #pragma unroll
    for (int kk = 0; kk < 2; ++kk)
        aq[kk] = *reinterpret_cast<const half8*>(&Qs[w*16 + (l & 15)][((l >> 4) * 8) + kk * 32]);
    float nlr[4];
    #pragma unroll
    for (int rr = 0; rr < 4; ++rr) nlr[rr] = -lrm_s[w*16 + ((l >> 4) << 2) + rr];

    f32x4 pv[4];
    #pragma unroll
    for (int fd = 0; fd < 4; ++fd) pv[fd] = (f32x4){0.f,0.f,0.f,0.f};
    float dsum[4] = {0.f, 0.f, 0.f, 0.f};

    for (int jc = 0; jc < 16; ++jc) {
        const int j0 = jc * 64;
        __syncthreads();   // previous chunk's PV reads complete
        #pragma unroll
        for (int p = 0; p < 2; ++p) {
            int r = (t >> 3) + p * 32, c = (t & 7) * 8;
            *reinterpret_cast<half8*>(&Ks[r][c]) =
                *reinterpret_cast<const half8*>(&kh[(((size_t)bh * SEQ) + j0 + r) * DHEAD + c]);
            *reinterpret_cast<half8*>(&Vs[r][c]) =
                *reinterpret_cast<const half8*>(&vt[(((size_t)bh * DHEAD) + r) * SEQ + j0 + c]);
        }
        if (t < 64) lcr_s[t] = lcr[(size_t)bh * SEQ + j0 + t];
        __syncthreads();

        // QK^T + transform -> Ps (per-wave slice)
        #pragma unroll
        for (int fj = 0; fj < 4; ++fj) {
            half8 kb0 = *reinterpret_cast<const half8*>(&Ks[fj*16 + (l & 15)][((l >> 4) * 8)]);
            half8 kb1 = *reinterpret_cast<const half8*>(&Ks[fj*16 + (l & 15)][((l >> 4) * 8) + 32]);
            f32x4 cfr = (f32x4){0.f,0.f,0.f,0.f};
            cfr = __builtin_amdgcn_mfma_f32_16x16x32_f16(aq[0], kb0, cfr, 0, 0, 0);
            cfr = __builtin_amdgcn_mfma_f32_16x16x32_f16(aq[1], kb1, cfr, 0, 0, 0);
            float base = lcr_s[fj * 16 + (l & 15)];
            #pragma unroll
            for (int rr = 0; rr < 4; ++rr) {
                float lg = spfns_lg(cfr[rr]);
                float pp = __builtin_amdgcn_exp2f(fmaf(lg, -PEXP, base + nlr[rr]));
                dsum[rr] += pp;
                Ps[w][((l >> 4) << 2) + rr][fj * 16 + (l & 15)] = (h16)pp;
            }
        }
        __syncthreads();   // Ps visible

        // PV
        half8 pa0 = *reinterpret_cast<const half8*>(&Ps[w][l & 15][((l >> 4) * 8)]);
        half8 pa1 = *reinterpret_cast<const half8*>(&Ps[w][l & 15][((l >> 4) * 8) + 32]);
        #pragma unroll
        for (int fd = 0; fd < 4; ++fd) {
            half8 vb0 = *reinterpret_cast<const half8*>(&Vs[fd*16 + (l & 15)][((l >> 4) * 8)]);
            half8 vb1 = *reinterpret_cast<const half8*>(&Vs[fd*16 + (l & 15)][((l >> 4) * 8) + 32]);
            pv[fd] = __builtin_amdgcn_mfma_f32_16x16x32_f16(pa0, vb0, pv[fd], 0, 0, 0);
            pv[fd] = __builtin_amdgcn_mfma_f32_16x16x32_f16(pa1, vb1, pv[fd], 0, 0, 0);
        }
    }

    // denominators: sum over the 16 j-lanes
    #pragma unroll
    for (int rr = 0; rr < 4; ++rr) {
        #pragma unroll
        for (int off = 1; off < 16; off <<= 1) dsum[rr] += __shfl_xor(dsum[rr], off);
    }

    const int b = bh >> 4, h = bh & 15;
    #pragma unroll
    for (int rr = 0; rr < 4; ++rr) {
        float inv = 1.0f / dsum[rr];
        int s = i0 + w * 16 + ((l >> 4) << 2) + rr;
        #pragma unroll
        for (int fd = 0; fd < 4; ++fd) {
            aoh[((size_t)(b * SEQ + s)) * DMODEL + h * DHEAD + fd * 16 + (l & 15)] =
                (h16)(pv[fd][rr] * inv);
        }
    }
}

// ---------------------------------------------------------------------------
extern "C" void kernel_launch(void* const* d_in, const int* in_sizes, int n_in,
                              void* d_out, int out_size, void* d_ws, size_t ws_size,
                              hipStream_t stream)
{
    (void)in_sizes; (void)n_in; (void)out_size; (void)ws_size;
    const float* x  = (const float*)d_in[0];
    const float* wq = (const float*)d_in[1];
    const float* bq = (const float*)d_in[2];
    const float* wk = (const float*)d_in[3];
    const float* bk = (const float*)d_in[4];
    const float* wv = (const float*)d_in[5];
    const float* bv = (const float*)d_in[6];
    const float* wo = (const float*)d_in[7];
    const float* bo = (const float*)d_in[8];
    float* out = (float*)d_out;

    // workspace layout (halves first, then f32/u32)
    h16* ws16 = (h16*)d_ws;
    const size_t NX  = (size_t)NROWS * DMODEL;      // 4,194,304
    const size_t NW3 = (size_t)3 * DMODEL * DMODEL; // 3,145,728
    const size_t NW1 = (size_t)DMODEL * DMODEL;     // 1,048,576
    const size_t NH  = (size_t)BH * SEQ * DHEAD;    // 4,194,304
    h16* xh  = ws16;
    h16* wt3 = xh  + NX;
    h16* wot = wt3 + NW3;
    h16* qh  = wot + NW1;
    h16* kh  = qh  + NH;      // contiguous after qh (l2norm covers both)
    h16* vt  = kh  + NH;
    h16* aoh = vt  + NH;
    float* nc  = (float*)(aoh + NX);
    float* lcr = nc  + BH * SEQ;
    float* lrm = lcr + BH * SEQ;
    unsigned* rm_u = (unsigned*)(lrm + BH * SEQ);
    int* gacc = (int*)(rm_u + BH * SEQ);

    hipMemsetAsync(rm_u, 0xFF, (size_t)BH * SEQ * sizeof(unsigned), stream);
    hipMemsetAsync(gacc, 0, sizeof(int), stream);

    cvt_x<<<2048, 256, 0, stream>>>(x, xh);
    wtrans<<<dim3(16, 16, 4), 256, 0, stream>>>(wq, wk, wv, wo, wt3, wot);

    // q,k,v projections (d = 0..3071 over [wq|wk|wv])
    gemm_f16<<<dim3(32, 24), 256, 0, stream>>>(xh, wt3, bq, bk, bv,
                                               qh, kh, vt, nullptr, 0);
    l2norm_f16<<<(2 * BH * SEQ) / 16, 256, 0, stream>>>(qh);

    passA<<<dim3(16, BH), 256, 0, stream>>>(qh, kh, nc, rm_u, gacc);
    ncprep<<<256, 256, 0, stream>>>(nc, rm_u, gacc, lcr, lrm);
    passB<<<dim3(16, BH), 256, 0, stream>>>(qh, kh, vt, lcr, lrm, aoh);

    gemm_f16<<<dim3(32, 8), 256, 0, stream>>>(aoh, wot, bo, nullptr, nullptr,
                                              nullptr, nullptr, nullptr, out, 1);
}

// Round 6
// 214.219 us; speedup vs baseline: 4.6307x; 1.0637x over previous
//
#include <hip/hip_runtime.h>
#include <hip/hip_bf16.h>
#include <cstdint>
#include <cstddef>

// ---------------- problem constants ----------------
#define BATCH  4
#define SEQ    1024
#define NHEAD  16
#define DHEAD  64
#define DMODEL 1024
#define NROWS  4096          // BATCH*SEQ
#define BH     64            // BATCH*NHEAD
#define CLIPV  0.999999f
#define PEXP   65.0f         // d_intrinsic + alpha

typedef _Float16 h16;
typedef _Float16 half8 __attribute__((ext_vector_type(8)));
typedef _Float16 half4 __attribute__((ext_vector_type(4)));
typedef __fp16   fp16x2 __attribute__((ext_vector_type(2)));
typedef float    f32x4 __attribute__((ext_vector_type(4)));

// lg = log2(1 + acos(clip(d))).  score = 2^(-65*lg).
// acos via AS 4.4.46 minimax (|err|<=2e-8): acos(a)=sqrt(1-a)*p7(a), a in [0,1].
__device__ __forceinline__ float spfns_lg(float d) {
    d = __builtin_amdgcn_fmed3f(d, -CLIPV, CLIPV);
    float a = fabsf(d);
    float s = __builtin_amdgcn_sqrtf(1.0f - a);
    float p = -0.0012624911f;
    p = fmaf(p, a,  0.0066700901f);
    p = fmaf(p, a, -0.0170881256f);
    p = fmaf(p, a,  0.0308918810f);
    p = fmaf(p, a, -0.0501743046f);
    p = fmaf(p, a,  0.0889789874f);
    p = fmaf(p, a, -0.2145988016f);
    p = fmaf(p, a,  1.5707963050f);
    float r = s * p;
    float g = (d >= 0.0f) ? r : (3.14159265358979f - r);
    return __builtin_amdgcn_logf(1.0f + g);
}

// pack two f32 -> 2x f16 (RTZ), returned as a 32-bit word
__device__ __forceinline__ unsigned pk_h2(float lo, float hi) {
    fp16x2 v = __builtin_amdgcn_cvt_pkrtz(lo, hi);
    return __builtin_bit_cast(unsigned, v);
}

// ---------------------------------------------------------------------------
// K1: x f32 -> xh f16
// ---------------------------------------------------------------------------
__global__ __launch_bounds__(256) void cvt_x(const float* __restrict__ x,
                                             h16* __restrict__ xh)
{
    size_t i = ((size_t)blockIdx.x * 256 + threadIdx.x) * 8;
    float4 a = *reinterpret_cast<const float4*>(&x[i]);
    float4 b = *reinterpret_cast<const float4*>(&x[i + 4]);
    half8 o;
    o[0]=(h16)a.x; o[1]=(h16)a.y; o[2]=(h16)a.z; o[3]=(h16)a.w;
    o[4]=(h16)b.x; o[5]=(h16)b.y; o[6]=(h16)b.z; o[7]=(h16)b.w;
    *reinterpret_cast<half8*>(&xh[i]) = o;
}

// ---------------------------------------------------------------------------
// K2: transpose+convert W [k][d] f32 -> Wt [d][k] f16.  z selects matrix.
// ---------------------------------------------------------------------------
__global__ __launch_bounds__(256) void wtrans(const float* __restrict__ wq,
                                              const float* __restrict__ wk,
                                              const float* __restrict__ wv,
                                              const float* __restrict__ wo,
                                              h16* __restrict__ wt3,
                                              h16* __restrict__ wot)
{
    __shared__ float T[64][65];
    const int k0 = blockIdx.x * 64, d0 = blockIdx.y * 64, z = blockIdx.z;
    const float* src = (z==0)?wq:(z==1)?wk:(z==2)?wv:wo;
    h16* dst = (z==3) ? wot : (wt3 + (size_t)z * 1024 * 1024);
    const int t = threadIdx.x;

    #pragma unroll
    for (int p = 0; p < 4; ++p) {
        int k = (t >> 4) + p * 16;
        int c = (t & 15) * 4;
        float4 v = *reinterpret_cast<const float4*>(&src[(size_t)(k0 + k) * 1024 + d0 + c]);
        T[c + 0][k] = v.x; T[c + 1][k] = v.y; T[c + 2][k] = v.z; T[c + 3][k] = v.w;
    }
    __syncthreads();
    #pragma unroll
    for (int p = 0; p < 2; ++p) {
        int dl = (t >> 3) + p * 32;
        int c  = (t & 7) * 8;
        half8 o;
        #pragma unroll
        for (int e = 0; e < 8; ++e) o[e] = (h16)T[dl][c + e];
        *reinterpret_cast<half8*>(&dst[(size_t)(d0 + dl) * 1024 + k0 + c]) = o;
    }
}

// ---------------------------------------------------------------------------
// K3: C = A(f16) @ Bt(f16)^T + bias.  128x128 tile, BK=64, 4 waves (2x2).
// mode 0: d in [0,3072): q/k -> head-major f16, v -> transposed vt f16.
// mode 1: d in [0,1024): out f32 row-major.
// ---------------------------------------------------------------------------
__global__ __launch_bounds__(256) void gemm_f16(const h16* __restrict__ A,
                                                const h16* __restrict__ Bt,
                                                const float* __restrict__ b0,
                                                const float* __restrict__ b1,
                                                const float* __restrict__ b2,
                                                h16* __restrict__ oq,
                                                h16* __restrict__ ok,
                                                h16* __restrict__ ovt,
                                                float* __restrict__ of32,
                                                int mode)
{
    __shared__ __align__(16) h16 As[128][72];
    __shared__ __align__(16) h16 Bs[128][72];
    const int n0 = blockIdx.x * 128, d0 = blockIdx.y * 128;
    const int t = threadIdx.x, l = t & 63, w = t >> 6;
    const int wr = (w >> 1) * 64, wc = (w & 1) * 64;

    f32x4 acc[4][4];
    #pragma unroll
    for (int i = 0; i < 4; ++i)
        #pragma unroll
        for (int j = 0; j < 4; ++j) acc[i][j] = (f32x4){0.f,0.f,0.f,0.f};

    for (int k0 = 0; k0 < 1024; k0 += 64) {
        __syncthreads();
        #pragma unroll
        for (int p = 0; p < 4; ++p) {
            int r = (t >> 3) + p * 32, c = (t & 7) * 8;
            *reinterpret_cast<half8*>(&As[r][c]) =
                *reinterpret_cast<const half8*>(&A[(size_t)(n0 + r) * 1024 + k0 + c]);
            *reinterpret_cast<half8*>(&Bs[r][c]) =
                *reinterpret_cast<const half8*>(&Bt[(size_t)(d0 + r) * 1024 + k0 + c]);
        }
        __syncthreads();
        #pragma unroll
        for (int kk = 0; kk < 2; ++kk) {
            half8 a[4], b[4];
            #pragma unroll
            for (int fi = 0; fi < 4; ++fi)
                a[fi] = *reinterpret_cast<const half8*>(&As[wr + fi*16 + (l & 15)][((l >> 4) * 8) + kk * 32]);
            #pragma unroll
            for (int fj = 0; fj < 4; ++fj)
                b[fj] = *reinterpret_cast<const half8*>(&Bs[wc + fj*16 + (l & 15)][((l >> 4) * 8) + kk * 32]);
            #pragma unroll
            for (int fi = 0; fi < 4; ++fi)
                #pragma unroll
                for (int fj = 0; fj < 4; ++fj)
                    acc[fi][fj] = __builtin_amdgcn_mfma_f32_16x16x32_f16(a[fi], b[fj], acc[fi][fj], 0, 0, 0);
        }
    }

    // epilogue
    #pragma unroll
    for (int fi = 0; fi < 4; ++fi) {
        #pragma unroll
        for (int fj = 0; fj < 4; ++fj) {
            int d = d0 + wc + fj * 16 + (l & 15);
            int s0n = n0 + wr + fi * 16 + ((l >> 4) << 2);
            if (mode == 0) {
                int mat = d >> 10, d1 = d & 1023, h = d1 >> 6, dh = d1 & 63;
                const float* bp = (mat == 0) ? b0 : (mat == 1) ? b1 : b2;
                float bias = bp[d1];
                if (mat == 2) {
                    int b = s0n >> 10, s0 = s0n & 1023;
                    half4 o;
                    #pragma unroll
                    for (int rr = 0; rr < 4; ++rr) o[rr] = (h16)(acc[fi][fj][rr] + bias);
                    *reinterpret_cast<half4*>(&ovt[(((size_t)(b * NHEAD + h)) * DHEAD + dh) * SEQ + s0]) = o;
                } else {
                    h16* dst = (mat == 0) ? oq : ok;
                    #pragma unroll
                    for (int rr = 0; rr < 4; ++rr) {
                        int n = s0n + rr, b = n >> 10, s = n & 1023;
                        dst[(((size_t)(b * NHEAD + h)) * SEQ + s) * DHEAD + dh] = (h16)(acc[fi][fj][rr] + bias);
                    }
                }
            } else {
                float bias = b0[d];
                #pragma unroll
                for (int rr = 0; rr < 4; ++rr) {
                    int n = s0n + rr;
                    of32[(size_t)n * DMODEL + d] = acc[fi][fj][rr] + bias;
                }
            }
        }
    }
}

// ---------------------------------------------------------------------------
// K4: L2-normalize rows of 64 f16 (qh and kh are contiguous).
// ---------------------------------------------------------------------------
__global__ __launch_bounds__(256) void l2norm_f16(h16* __restrict__ buf)
{
    const int t = threadIdx.x;
    size_t row = (size_t)blockIdx.x * 16 + (t >> 4);
    int c = (t & 15) * 4;
    half4 v = *reinterpret_cast<const half4*>(&buf[row * 64 + c]);
    float f0 = (float)v[0], f1 = (float)v[1], f2 = (float)v[2], f3 = (float)v[3];
    float s = f0*f0 + f1*f1 + f2*f2 + f3*f3;
    #pragma unroll
    for (int off = 1; off < 16; off <<= 1) s += __shfl_xor(s, off);
    float sc = __builtin_amdgcn_rcpf(fmaxf(__builtin_amdgcn_sqrtf(s), 1e-12f));
    half4 o;
    o[0] = (h16)(f0 * sc); o[1] = (h16)(f1 * sc); o[2] = (h16)(f2 * sc); o[3] = (h16)(f3 * sc);
    *reinterpret_cast<half4*>(&buf[row * 64 + c]) = o;
}

// ---------------------------------------------------------------------------
// K5 pass A (swapped MFMA): per (jt, bh).  D = mfma(K, Q): lane holds
// j = 16*fj + 4*(l>>4) + rr (regs), i = w*16 + (l&15) (lane).
// ncacc[16] in regs (col sums); per-it row-min via 2 shfl + 1 atomic.
// ---------------------------------------------------------------------------
__global__ __launch_bounds__(256) void passA(const h16* __restrict__ qh,
                                             const h16* __restrict__ kh,
                                             float* __restrict__ nc,
                                             unsigned* __restrict__ rm_u,
                                             int* __restrict__ gacc)
{
    __shared__ __align__(16) h16 Ks[64][72];
    __shared__ __align__(16) h16 Qs[64][72];
    __shared__ float red[4][64];
    const int jt = blockIdx.x, bh = blockIdx.y;
    const int j0 = jt * 64;
    const int t = threadIdx.x, l = t & 63, w = t >> 6;

    // stage K tile (rows j0..j0+63), hoist fragments to regs
    #pragma unroll
    for (int p = 0; p < 2; ++p) {
        int r = (t >> 3) + p * 32, c = (t & 7) * 8;
        *reinterpret_cast<half8*>(&Ks[r][c]) =
            *reinterpret_cast<const half8*>(&kh[(((size_t)bh * SEQ) + j0 + r) * DHEAD + c]);
    }
    __syncthreads();

    half8 kfr[4][2];
    #pragma unroll
    for (int fj = 0; fj < 4; ++fj)
        #pragma unroll
        for (int kk = 0; kk < 2; ++kk)
            kfr[fj][kk] = *reinterpret_cast<const half8*>(&Ks[fj*16 + (l & 15)][((l >> 4) * 8) + kk * 32]);

    float ncacc[16];
    #pragma unroll
    for (int x = 0; x < 16; ++x) ncacc[x] = 0.f;

    for (int it = 0; it < 16; ++it) {
        __syncthreads();
        #pragma unroll
        for (int p = 0; p < 2; ++p) {
            int r = (t >> 3) + p * 32, c = (t & 7) * 8;
            *reinterpret_cast<half8*>(&Qs[r][c]) =
                *reinterpret_cast<const half8*>(&qh[(((size_t)bh * SEQ) + it*64 + r) * DHEAD + c]);
        }
        __syncthreads();

        half8 aq0 = *reinterpret_cast<const half8*>(&Qs[w*16 + (l & 15)][((l >> 4) * 8)]);
        half8 aq1 = *reinterpret_cast<const half8*>(&Qs[w*16 + (l & 15)][((l >> 4) * 8) + 32]);

        float mloc = 1e30f;
        #pragma unroll
        for (int fj = 0; fj < 4; ++fj) {
            f32x4 cfr = (f32x4){0.f,0.f,0.f,0.f};
            cfr = __builtin_amdgcn_mfma_f32_16x16x32_f16(kfr[fj][0], aq0, cfr, 0, 0, 0);
            cfr = __builtin_amdgcn_mfma_f32_16x16x32_f16(kfr[fj][1], aq1, cfr, 0, 0, 0);
            #pragma unroll
            for (int rr = 0; rr < 4; ++rr) {
                float lg = spfns_lg(cfr[rr]);
                ncacc[fj*4 + rr] += __builtin_amdgcn_exp2f(-PEXP * lg);
                mloc = fminf(mloc, lg);
            }
        }
        // row-min over all 64 j of this block: fold lane groups, 1 atomic
        mloc = fminf(mloc, __shfl_xor(mloc, 16));
        mloc = fminf(mloc, __shfl_xor(mloc, 32));
        if (l < 16)
            atomicMin(&rm_u[(size_t)bh * SEQ + it*64 + w*16 + l], __float_as_uint(mloc));
    }

    // column sums: reduce over the 16 i-lanes (bits 0..3)
    #pragma unroll
    for (int x = 0; x < 16; ++x) {
        #pragma unroll
        for (int off = 1; off < 16; off <<= 1)
            ncacc[x] += __shfl_xor(ncacc[x], off);
    }
    if ((l & 15) == 0) {
        #pragma unroll
        for (int x = 0; x < 16; ++x)
            red[w][(x >> 2) * 16 + (l >> 4) * 4 + (x & 3)] = ncacc[x];
    }
    __syncthreads();
    if (t < 64) {
        float v = red[0][t] + red[1][t] + red[2][t] + red[3][t];
        nc[(size_t)bh * SEQ + j0 + t] = v;
        atomicAdd(gacc, (int)rintf(__builtin_amdgcn_logf(v) * 64.0f));
    }
}

// ---------------------------------------------------------------------------
// K6: lcr = log2 shift for columns; lrm = row max of t2 = -65*min lg.
// ---------------------------------------------------------------------------
__global__ __launch_bounds__(256) void ncprep(const float* __restrict__ nc,
                                              const unsigned* __restrict__ rm_u,
                                              const int* __restrict__ gacc,
                                              float* __restrict__ lcr,
                                              float* __restrict__ lrm)
{
    int i = blockIdx.x * 256 + threadIdx.x;
    float Lm = (float)(*gacc) / (65536.0f * 64.0f);   // mean log2(nc)
    lcr[i] = -0.5f * (__builtin_amdgcn_logf(nc[i]) - Lm);
    lrm[i] = -PEXP * __uint_as_float(rm_u[i]);
}

// ---------------------------------------------------------------------------
// K7 pass B (swapped MFMA): per (it, bh).  QK^T via mfma(K,Q): lane holds
// P[j = 16fj+4g+rr][i = l&15] -> packed b64 Ps writes.  PV + ones-column
// MFMA for the denominator.  Q staged through the Ps buffer (LDS alias).
// ---------------------------------------------------------------------------
__global__ __launch_bounds__(256) void passB(const h16* __restrict__ qh,
                                             const h16* __restrict__ kh,
                                             const h16* __restrict__ vt,
                                             const float* __restrict__ lcr,
                                             const float* __restrict__ lrm,
                                             h16* __restrict__ aoh)
{
    __shared__ __align__(16) h16 Ks[64][72];
    __shared__ __align__(16) h16 Vs[64][72];
    __shared__ __align__(16) h16 Ps[4][16][72];   // per-wave P tiles; also Q staging
    __shared__ float lcr_s[64];
    __shared__ float lrm_s[64];

    const int it = blockIdx.x, bh = blockIdx.y;
    const int i0 = it * 64;
    const int t = threadIdx.x, l = t & 63, w = t >> 6;
    h16* Pflat = &Ps[0][0][0];   // [64][72] view

    // stage Q tile into Ps area + lrm
    #pragma unroll
    for (int p = 0; p < 2; ++p) {
        int r = (t >> 3) + p * 32, c = (t & 7) * 8;
        *reinterpret_cast<half8*>(&Pflat[r * 72 + c]) =
            *reinterpret_cast<const half8*>(&qh[(((size_t)bh * SEQ) + i0 + r) * DHEAD + c]);
    }
    if (t < 64) lrm_s[t] = lrm[(size_t)bh * SEQ + i0 + t];
    __syncthreads();

    half8 aq0 = *reinterpret_cast<const half8*>(&Pflat[(w*16 + (l & 15)) * 72 + ((l >> 4) * 8)]);
    half8 aq1 = *reinterpret_cast<const half8*>(&Pflat[(w*16 + (l & 15)) * 72 + ((l >> 4) * 8) + 32]);
    const float nlr = -lrm_s[w*16 + (l & 15)];

    // ones B-fragment: row n==0 of ones -> denominator column
    half8 ones8;
    {
        h16 ov = (h16)(((l & 15) == 0) ? 1.0f : 0.0f);
        #pragma unroll
        for (int e = 0; e < 8; ++e) ones8[e] = ov;
    }

    f32x4 pv[4];
    #pragma unroll
    for (int fd = 0; fd < 4; ++fd) pv[fd] = (f32x4){0.f,0.f,0.f,0.f};
    f32x4 pvden = (f32x4){0.f,0.f,0.f,0.f};

    for (int jc = 0; jc < 16; ++jc) {
        const int j0 = jc * 64;
        __syncthreads();   // protect Ks/Vs reuse (Ps is wave-local)
        #pragma unroll
        for (int p = 0; p < 2; ++p) {
            int r = (t >> 3) + p * 32, c = (t & 7) * 8;
            *reinterpret_cast<half8*>(&Ks[r][c]) =
                *reinterpret_cast<const half8*>(&kh[(((size_t)bh * SEQ) + j0 + r) * DHEAD + c]);
            *reinterpret_cast<half8*>(&Vs[r][c]) =
                *reinterpret_cast<const half8*>(&vt[(((size_t)bh * DHEAD) + r) * SEQ + j0 + c]);
        }
        if (t < 64) lcr_s[t] = lcr[(size_t)bh * SEQ + j0 + t];
        __syncthreads();

        // QK^T (swapped) + transform -> packed Ps writes
        #pragma unroll
        for (int fj = 0; fj < 4; ++fj) {
            half8 kb0 = *reinterpret_cast<const half8*>(&Ks[fj*16 + (l & 15)][((l >> 4) * 8)]);
            half8 kb1 = *reinterpret_cast<const half8*>(&Ks[fj*16 + (l & 15)][((l >> 4) * 8) + 32]);
            f32x4 cfr = (f32x4){0.f,0.f,0.f,0.f};
            cfr = __builtin_amdgcn_mfma_f32_16x16x32_f16(kb0, aq0, cfr, 0, 0, 0);
            cfr = __builtin_amdgcn_mfma_f32_16x16x32_f16(kb1, aq1, cfr, 0, 0, 0);
            float4 lc4 = *reinterpret_cast<const float4*>(&lcr_s[fj*16 + (l >> 4) * 4]);
            float pp0 = __builtin_amdgcn_exp2f(fmaf(spfns_lg(cfr[0]), -PEXP, lc4.x + nlr));
            float pp1 = __builtin_amdgcn_exp2f(fmaf(spfns_lg(cfr[1]), -PEXP, lc4.y + nlr));
            float pp2 = __builtin_amdgcn_exp2f(fmaf(spfns_lg(cfr[2]), -PEXP, lc4.z + nlr));
            float pp3 = __builtin_amdgcn_exp2f(fmaf(spfns_lg(cfr[3]), -PEXP, lc4.w + nlr));
            uint2 pk;
            pk.x = pk_h2(pp0, pp1);
            pk.y = pk_h2(pp2, pp3);
            *reinterpret_cast<uint2*>(&Ps[w][l & 15][fj*16 + (l >> 4) * 4]) = pk;
        }
        // no barrier: Ps[w] is wave-local; same-wave DS ordering suffices

        // PV (+ denominator via ones column)
        half8 pa0 = *reinterpret_cast<const half8*>(&Ps[w][l & 15][((l >> 4) * 8)]);
        half8 pa1 = *reinterpret_cast<const half8*>(&Ps[w][l & 15][((l >> 4) * 8) + 32]);
        #pragma unroll
        for (int fd = 0; fd < 4; ++fd) {
            half8 vb0 = *reinterpret_cast<const half8*>(&Vs[fd*16 + (l & 15)][((l >> 4) * 8)]);
            half8 vb1 = *reinterpret_cast<const half8*>(&Vs[fd*16 + (l & 15)][((l >> 4) * 8) + 32]);
            pv[fd] = __builtin_amdgcn_mfma_f32_16x16x32_f16(pa0, vb0, pv[fd], 0, 0, 0);
            pv[fd] = __builtin_amdgcn_mfma_f32_16x16x32_f16(pa1, vb1, pv[fd], 0, 0, 0);
        }
        pvden = __builtin_amdgcn_mfma_f32_16x16x32_f16(pa0, ones8, pvden, 0, 0, 0);
        pvden = __builtin_amdgcn_mfma_f32_16x16x32_f16(pa1, ones8, pvden, 0, 0, 0);
    }

    // epilogue: denominator lives in lanes with (l&15)==0 of each 16-group
    const int b = bh >> 4, h = bh & 15;
    #pragma unroll
    for (int rr = 0; rr < 4; ++rr) {
        float ds = __shfl(pvden[rr], l & 48);
        float inv = __builtin_amdgcn_rcpf(ds);
        int s = i0 + w * 16 + ((l >> 4) << 2) + rr;
        #pragma unroll
        for (int fd = 0; fd < 4; ++fd) {
            aoh[((size_t)(b * SEQ + s)) * DMODEL + h * DHEAD + fd * 16 + (l & 15)] =
                (h16)(pv[fd][rr] * inv);
        }
    }
}

// ---------------------------------------------------------------------------
extern "C" void kernel_launch(void* const* d_in, const int* in_sizes, int n_in,
                              void* d_out, int out_size, void* d_ws, size_t ws_size,
                              hipStream_t stream)
{
    (void)in_sizes; (void)n_in; (void)out_size; (void)ws_size;
    const float* x  = (const float*)d_in[0];
    const float* wq = (const float*)d_in[1];
    const float* bq = (const float*)d_in[2];
    const float* wk = (const float*)d_in[3];
    const float* bk = (const float*)d_in[4];
    const float* wv = (const float*)d_in[5];
    const float* bv = (const float*)d_in[6];
    const float* wo = (const float*)d_in[7];
    const float* bo = (const float*)d_in[8];
    float* out = (float*)d_out;

    // workspace layout (halves first, then f32/u32)
    h16* ws16 = (h16*)d_ws;
    const size_t NX  = (size_t)NROWS * DMODEL;      // 4,194,304
    const size_t NW3 = (size_t)3 * DMODEL * DMODEL; // 3,145,728
    const size_t NW1 = (size_t)DMODEL * DMODEL;     // 1,048,576
    const size_t NH  = (size_t)BH * SEQ * DHEAD;    // 4,194,304
    h16* xh  = ws16;
    h16* wt3 = xh  + NX;
    h16* wot = wt3 + NW3;
    h16* qh  = wot + NW1;
    h16* kh  = qh  + NH;      // contiguous after qh (l2norm covers both)
    h16* vt  = kh  + NH;
    h16* aoh = vt  + NH;
    float* nc  = (float*)(aoh + NX);
    float* lcr = nc  + BH * SEQ;
    float* lrm = lcr + BH * SEQ;
    unsigned* rm_u = (unsigned*)(lrm + BH * SEQ);
    int* gacc = (int*)(rm_u + BH * SEQ);

    hipMemsetAsync(rm_u, 0xFF, (size_t)BH * SEQ * sizeof(unsigned), stream);
    hipMemsetAsync(gacc, 0, sizeof(int), stream);

    cvt_x<<<2048, 256, 0, stream>>>(x, xh);
    wtrans<<<dim3(16, 16, 4), 256, 0, stream>>>(wq, wk, wv, wo, wt3, wot);

    // q,k,v projections (d = 0..3071 over [wq|wk|wv])
    gemm_f16<<<dim3(32, 24), 256, 0, stream>>>(xh, wt3, bq, bk, bv,
                                               qh, kh, vt, nullptr, 0);
    l2norm_f16<<<(2 * BH * SEQ) / 16, 256, 0, stream>>>(qh);

    passA<<<dim3(16, BH), 256, 0, stream>>>(qh, kh, nc, rm_u, gacc);
    ncprep<<<256, 256, 0, stream>>>(nc, rm_u, gacc, lcr, lrm);
    passB<<<dim3(16, BH), 256, 0, stream>>>(qh, kh, vt, lcr, lrm, aoh);

    gemm_f16<<<dim3(32, 8), 256, 0, stream>>>(aoh, wot, bo, nullptr, nullptr,
                                              nullptr, nullptr, nullptr, out, 1);
}

// Round 7
// 208.545 us; speedup vs baseline: 4.7568x; 1.0272x over previous
//
#include <hip/hip_runtime.h>
#include <hip/hip_bf16.h>
#include <cstdint>
#include <cstddef>

// ---------------- problem constants ----------------
#define BATCH  4
#define SEQ    1024
#define NHEAD  16
#define DHEAD  64
#define DMODEL 1024
#define NROWS  4096          // BATCH*SEQ
#define BH     64            // BATCH*NHEAD
#define CLIPV  0.999999f
#define PEXP   65.0f         // d_intrinsic + alpha

// u16 quantization of t = -65*lg, t in [-133.27, 0]
#define QOFF   133.5f
#define QK_    490.8988764f           // 65535/133.5
#define QINV   0.0020370716f          // 133.5/65535
#define QC     65535.5f               // QOFF*QK_ + 0.5 (round-nearest)

typedef _Float16 h16;
typedef _Float16 half8 __attribute__((ext_vector_type(8)));
typedef _Float16 half4 __attribute__((ext_vector_type(4)));
typedef __fp16   fp16x2 __attribute__((ext_vector_type(2)));
typedef float    f32x4 __attribute__((ext_vector_type(4)));

typedef const __attribute__((address_space(1))) void gas_void;
typedef __attribute__((address_space(3))) void las_void;
#define GLOAD_LDS16(g, l) \
    __builtin_amdgcn_global_load_lds((gas_void*)(g), (las_void*)(l), 16, 0, 0)

// lg = log2(1 + acos(clip(d))).  score = 2^(-65*lg).
// acos via AS 4.4.46 minimax (|err|<=2e-8): acos(a)=sqrt(1-a)*p7(a), a in [0,1].
__device__ __forceinline__ float spfns_lg(float d) {
    d = __builtin_amdgcn_fmed3f(d, -CLIPV, CLIPV);
    float a = fabsf(d);
    float s = __builtin_amdgcn_sqrtf(1.0f - a);
    float p = -0.0012624911f;
    p = fmaf(p, a,  0.0066700901f);
    p = fmaf(p, a, -0.0170881256f);
    p = fmaf(p, a,  0.0308918810f);
    p = fmaf(p, a, -0.0501743046f);
    p = fmaf(p, a,  0.0889789874f);
    p = fmaf(p, a, -0.2145988016f);
    p = fmaf(p, a,  1.5707963050f);
    float r = s * p;
    float g = (d >= 0.0f) ? r : (3.14159265358979f - r);
    return __builtin_amdgcn_logf(1.0f + g);
}

// pack two f32 -> 2x f16 (RTZ), returned as a 32-bit word
__device__ __forceinline__ unsigned pk_h2(float lo, float hi) {
    fp16x2 v = __builtin_amdgcn_cvt_pkrtz(lo, hi);
    return __builtin_bit_cast(unsigned, v);
}

// ---------------------------------------------------------------------------
// K1: x f32 -> xh f16
// ---------------------------------------------------------------------------
__global__ __launch_bounds__(256) void cvt_x(const float* __restrict__ x,
                                             h16* __restrict__ xh)
{
    size_t i = ((size_t)blockIdx.x * 256 + threadIdx.x) * 8;
    float4 a = *reinterpret_cast<const float4*>(&x[i]);
    float4 b = *reinterpret_cast<const float4*>(&x[i + 4]);
    half8 o;
    o[0]=(h16)a.x; o[1]=(h16)a.y; o[2]=(h16)a.z; o[3]=(h16)a.w;
    o[4]=(h16)b.x; o[5]=(h16)b.y; o[6]=(h16)b.z; o[7]=(h16)b.w;
    *reinterpret_cast<half8*>(&xh[i]) = o;
}

// ---------------------------------------------------------------------------
// K2: transpose+convert W [k][d] f32 -> Wt [d][k] f16.  z selects matrix.
// ---------------------------------------------------------------------------
__global__ __launch_bounds__(256) void wtrans(const float* __restrict__ wq,
                                              const float* __restrict__ wk,
                                              const float* __restrict__ wv,
                                              const float* __restrict__ wo,
                                              h16* __restrict__ wt3,
                                              h16* __restrict__ wot)
{
    __shared__ float T[64][65];
    const int k0 = blockIdx.x * 64, d0 = blockIdx.y * 64, z = blockIdx.z;
    const float* src = (z==0)?wq:(z==1)?wk:(z==2)?wv:wo;
    h16* dst = (z==3) ? wot : (wt3 + (size_t)z * 1024 * 1024);
    const int t = threadIdx.x;

    #pragma unroll
    for (int p = 0; p < 4; ++p) {
        int k = (t >> 4) + p * 16;
        int c = (t & 15) * 4;
        float4 v = *reinterpret_cast<const float4*>(&src[(size_t)(k0 + k) * 1024 + d0 + c]);
        T[c + 0][k] = v.x; T[c + 1][k] = v.y; T[c + 2][k] = v.z; T[c + 3][k] = v.w;
    }
    __syncthreads();
    #pragma unroll
    for (int p = 0; p < 2; ++p) {
        int dl = (t >> 3) + p * 32;
        int c  = (t & 7) * 8;
        half8 o;
        #pragma unroll
        for (int e = 0; e < 8; ++e) o[e] = (h16)T[dl][c + e];
        *reinterpret_cast<half8*>(&dst[(size_t)(d0 + dl) * 1024 + k0 + c]) = o;
    }
}

// ---------------------------------------------------------------------------
// K3: C = A(f16) @ Bt(f16)^T + bias.  128x128 tile, BK=64, 4 waves (2x2).
// Staging via global_load_lds width-16 into linear [128][64] LDS (m97 style).
// mode 0: d in [0,3072): q/k -> head-major f16, v -> transposed vt f16.
// mode 1: d in [0,1024): out f32 row-major.
// ---------------------------------------------------------------------------
__global__ __launch_bounds__(256) void gemm_f16(const h16* __restrict__ A,
                                                const h16* __restrict__ Bt,
                                                const float* __restrict__ b0,
                                                const float* __restrict__ b1,
                                                const float* __restrict__ b2,
                                                h16* __restrict__ oq,
                                                h16* __restrict__ ok,
                                                h16* __restrict__ ovt,
                                                float* __restrict__ of32,
                                                int mode)
{
    __shared__ __align__(16) h16 As[128][64];
    __shared__ __align__(16) h16 Bs[128][64];
    const int n0 = blockIdx.x * 128, d0 = blockIdx.y * 128;
    const int t = threadIdx.x, l = t & 63, w = t >> 6;
    const int wr = (w >> 1) * 64, wc = (w & 1) * 64;
    const int lr = l >> 3, lc8 = (l & 7) * 8;   // staging row/col within 8-row slab

    f32x4 acc[4][4];
    #pragma unroll
    for (int i = 0; i < 4; ++i)
        #pragma unroll
        for (int j = 0; j < 4; ++j) acc[i][j] = (f32x4){0.f,0.f,0.f,0.f};

    for (int k0 = 0; k0 < 1024; k0 += 64) {
        __syncthreads();
        #pragma unroll
        for (int q = 0; q < 4; ++q) {
            int r = w * 32 + q * 8;
            GLOAD_LDS16(&A[(size_t)(n0 + r + lr) * 1024 + k0 + lc8], &As[r][0]);
            GLOAD_LDS16(&Bt[(size_t)(d0 + r + lr) * 1024 + k0 + lc8], &Bs[r][0]);
        }
        __syncthreads();
        #pragma unroll
        for (int kk = 0; kk < 2; ++kk) {
            half8 a[4], b[4];
            #pragma unroll
            for (int fi = 0; fi < 4; ++fi)
                a[fi] = *reinterpret_cast<const half8*>(&As[wr + fi*16 + (l & 15)][((l >> 4) * 8) + kk * 32]);
            #pragma unroll
            for (int fj = 0; fj < 4; ++fj)
                b[fj] = *reinterpret_cast<const half8*>(&Bs[wc + fj*16 + (l & 15)][((l >> 4) * 8) + kk * 32]);
            #pragma unroll
            for (int fi = 0; fi < 4; ++fi)
                #pragma unroll
                for (int fj = 0; fj < 4; ++fj)
                    acc[fi][fj] = __builtin_amdgcn_mfma_f32_16x16x32_f16(a[fi], b[fj], acc[fi][fj], 0, 0, 0);
        }
    }

    // epilogue
    #pragma unroll
    for (int fi = 0; fi < 4; ++fi) {
        #pragma unroll
        for (int fj = 0; fj < 4; ++fj) {
            int d = d0 + wc + fj * 16 + (l & 15);
            int s0n = n0 + wr + fi * 16 + ((l >> 4) << 2);
            if (mode == 0) {
                int mat = d >> 10, d1 = d & 1023, h = d1 >> 6, dh = d1 & 63;
                const float* bp = (mat == 0) ? b0 : (mat == 1) ? b1 : b2;
                float bias = bp[d1];
                if (mat == 2) {
                    int b = s0n >> 10, s0 = s0n & 1023;
                    half4 o;
                    #pragma unroll
                    for (int rr = 0; rr < 4; ++rr) o[rr] = (h16)(acc[fi][fj][rr] + bias);
                    *reinterpret_cast<half4*>(&ovt[(((size_t)(b * NHEAD + h)) * DHEAD + dh) * SEQ + s0]) = o;
                } else {
                    h16* dst = (mat == 0) ? oq : ok;
                    #pragma unroll
                    for (int rr = 0; rr < 4; ++rr) {
                        int n = s0n + rr, b = n >> 10, s = n & 1023;
                        dst[(((size_t)(b * NHEAD + h)) * SEQ + s) * DHEAD + dh] = (h16)(acc[fi][fj][rr] + bias);
                    }
                }
            } else {
                float bias = b0[d];
                #pragma unroll
                for (int rr = 0; rr < 4; ++rr) {
                    int n = s0n + rr;
                    of32[(size_t)n * DMODEL + d] = acc[fi][fj][rr] + bias;
                }
            }
        }
    }
}

// ---------------------------------------------------------------------------
// K4: L2-normalize rows of 64 f16 (qh and kh are contiguous).
// ---------------------------------------------------------------------------
__global__ __launch_bounds__(256) void l2norm_f16(h16* __restrict__ buf)
{
    const int t = threadIdx.x;
    size_t row = (size_t)blockIdx.x * 16 + (t >> 4);
    int c = (t & 15) * 4;
    half4 v = *reinterpret_cast<const half4*>(&buf[row * 64 + c]);
    float f0 = (float)v[0], f1 = (float)v[1], f2 = (float)v[2], f3 = (float)v[3];
    float s = f0*f0 + f1*f1 + f2*f2 + f3*f3;
    #pragma unroll
    for (int off = 1; off < 16; off <<= 1) s += __shfl_xor(s, off);
    float sc = __builtin_amdgcn_rcpf(fmaxf(__builtin_amdgcn_sqrtf(s), 1e-12f));
    half4 o;
    o[0] = (h16)(f0 * sc); o[1] = (h16)(f1 * sc); o[2] = (h16)(f2 * sc); o[3] = (h16)(f3 * sc);
    *reinterpret_cast<half4*>(&buf[row * 64 + c]) = o;
}

// ---------------------------------------------------------------------------
// K5 pass A (swapped MFMA): per (jt, bh).  D = mfma(K, Q): lane holds
// j = 16*fj + 4*(l>>4) + rr (regs), i = w*16 + (l&15) (lane).
// CACHED: additionally quantize t = -65*lg to u16 and store to Sw in the
// exact fragment layout passB consumes (coalesced uint2 per (it,fj)).
// ---------------------------------------------------------------------------
template<int CACHED>
__global__ __launch_bounds__(256) void passA(const h16* __restrict__ qh,
                                             const h16* __restrict__ kh,
                                             float* __restrict__ nc,
                                             unsigned* __restrict__ rm_u,
                                             int* __restrict__ gacc,
                                             unsigned short* __restrict__ Sw)
{
    __shared__ __align__(16) h16 Ks[64][72];
    __shared__ __align__(16) h16 Qs[64][72];
    __shared__ float red[4][64];
    const int jt = blockIdx.x, bh = blockIdx.y;
    const int j0 = jt * 64;
    const int t = threadIdx.x, l = t & 63, w = t >> 6;

    // stage K tile (rows j0..j0+63), hoist fragments to regs
    #pragma unroll
    for (int p = 0; p < 2; ++p) {
        int r = (t >> 3) + p * 32, c = (t & 7) * 8;
        *reinterpret_cast<half8*>(&Ks[r][c]) =
            *reinterpret_cast<const half8*>(&kh[(((size_t)bh * SEQ) + j0 + r) * DHEAD + c]);
    }
    __syncthreads();

    half8 kfr[4][2];
    #pragma unroll
    for (int fj = 0; fj < 4; ++fj)
        #pragma unroll
        for (int kk = 0; kk < 2; ++kk)
            kfr[fj][kk] = *reinterpret_cast<const half8*>(&Ks[fj*16 + (l & 15)][((l >> 4) * 8) + kk * 32]);

    float ncacc[16];
    #pragma unroll
    for (int x = 0; x < 16; ++x) ncacc[x] = 0.f;

    for (int it = 0; it < 16; ++it) {
        __syncthreads();
        #pragma unroll
        for (int p = 0; p < 2; ++p) {
            int r = (t >> 3) + p * 32, c = (t & 7) * 8;
            *reinterpret_cast<half8*>(&Qs[r][c]) =
                *reinterpret_cast<const half8*>(&qh[(((size_t)bh * SEQ) + it*64 + r) * DHEAD + c]);
        }
        __syncthreads();

        half8 aq0 = *reinterpret_cast<const half8*>(&Qs[w*16 + (l & 15)][((l >> 4) * 8)]);
        half8 aq1 = *reinterpret_cast<const half8*>(&Qs[w*16 + (l & 15)][((l >> 4) * 8) + 32]);

        float mloc = 1e30f;
        #pragma unroll
        for (int fj = 0; fj < 4; ++fj) {
            f32x4 cfr = (f32x4){0.f,0.f,0.f,0.f};
            cfr = __builtin_amdgcn_mfma_f32_16x16x32_f16(kfr[fj][0], aq0, cfr, 0, 0, 0);
            cfr = __builtin_amdgcn_mfma_f32_16x16x32_f16(kfr[fj][1], aq1, cfr, 0, 0, 0);
            unsigned uq[4];
            #pragma unroll
            for (int rr = 0; rr < 4; ++rr) {
                float lg = spfns_lg(cfr[rr]);
                float tt = lg * (-PEXP);
                ncacc[fj*4 + rr] += __builtin_amdgcn_exp2f(tt);
                mloc = fminf(mloc, lg);
                if (CACHED) uq[rr] = (unsigned)fmaf(tt, QK_, QC);
            }
            if (CACHED) {
                uint2 pkw;
                pkw.x = uq[0] | (uq[1] << 16);
                pkw.y = uq[2] | (uq[3] << 16);
                size_t sidx = (((((size_t)(bh*16 + jt)*16 + it)*4 + w)*4 + fj) << 8) + (size_t)l*4;
                *reinterpret_cast<uint2*>(&Sw[sidx]) = pkw;
            }
        }
        // row-min over all 64 j of this block: fold lane groups, 1 atomic
        mloc = fminf(mloc, __shfl_xor(mloc, 16));
        mloc = fminf(mloc, __shfl_xor(mloc, 32));
        if (l < 16)
            atomicMin(&rm_u[(size_t)bh * SEQ + it*64 + w*16 + l], __float_as_uint(mloc));
    }

    // column sums: reduce over the 16 i-lanes (bits 0..3)
    #pragma unroll
    for (int x = 0; x < 16; ++x) {
        #pragma unroll
        for (int off = 1; off < 16; off <<= 1)
            ncacc[x] += __shfl_xor(ncacc[x], off);
    }
    if ((l & 15) == 0) {
        #pragma unroll
        for (int x = 0; x < 16; ++x)
            red[w][(x >> 2) * 16 + (l >> 4) * 4 + (x & 3)] = ncacc[x];
    }
    __syncthreads();
    if (t < 64) {
        float v = red[0][t] + red[1][t] + red[2][t] + red[3][t];
        nc[(size_t)bh * SEQ + j0 + t] = v;
        atomicAdd(gacc, (int)rintf(__builtin_amdgcn_logf(v) * 64.0f));
    }
}

// ---------------------------------------------------------------------------
// K6: lcr = log2 shift for columns; lrm = row max of t2 = -65*min lg.
// ---------------------------------------------------------------------------
__global__ __launch_bounds__(256) void ncprep(const float* __restrict__ nc,
                                              const unsigned* __restrict__ rm_u,
                                              const int* __restrict__ gacc,
                                              float* __restrict__ lcr,
                                              float* __restrict__ lrm)
{
    int i = blockIdx.x * 256 + threadIdx.x;
    float Lm = (float)(*gacc) / (65536.0f * 64.0f);   // mean log2(nc)
    lcr[i] = -0.5f * (__builtin_amdgcn_logf(nc[i]) - Lm);
    lrm[i] = -PEXP * __uint_as_float(rm_u[i]);
}

// ---------------------------------------------------------------------------
// K7 pass B.  CACHED=1: read u16-quantized t from Sw (prefetched one chunk
// ahead), decode p = exp2(u*QINV + base), no QK^T at all.  CACHED=0: full
// recompute (swapped QK^T MFMA + transform).  Both: PV + ones-column MFMA.
// ---------------------------------------------------------------------------
template<int CACHED>
__global__ __launch_bounds__(256) void passB(const h16* __restrict__ qh,
                                             const h16* __restrict__ kh,
                                             const h16* __restrict__ vt,
                                             const float* __restrict__ lcr,
                                             const float* __restrict__ lrm,
                                             const unsigned short* __restrict__ Sw,
                                             h16* __restrict__ aoh)
{
    __shared__ __align__(16) h16 Ks[64][72];
    __shared__ __align__(16) h16 Vs[64][72];
    __shared__ __align__(16) h16 Ps[4][16][72];   // per-wave P tiles; also Q staging
    __shared__ float lcr_s[64];
    __shared__ float lrm_s[64];

    const int it = blockIdx.x, bh = blockIdx.y;
    const int i0 = it * 64;
    const int t = threadIdx.x, l = t & 63, w = t >> 6;
    h16* Pflat = &Ps[0][0][0];   // [64][72] view

    half8 aq0, aq1;
    if (!CACHED) {
        // stage Q tile into Ps area
        #pragma unroll
        for (int p = 0; p < 2; ++p) {
            int r = (t >> 3) + p * 32, c = (t & 7) * 8;
            *reinterpret_cast<half8*>(&Pflat[r * 72 + c]) =
                *reinterpret_cast<const half8*>(&qh[(((size_t)bh * SEQ) + i0 + r) * DHEAD + c]);
        }
    }
    if (t < 64) lrm_s[t] = lrm[(size_t)bh * SEQ + i0 + t];
    __syncthreads();

    if (!CACHED) {
        aq0 = *reinterpret_cast<const half8*>(&Pflat[(w*16 + (l & 15)) * 72 + ((l >> 4) * 8)]);
        aq1 = *reinterpret_cast<const half8*>(&Pflat[(w*16 + (l & 15)) * 72 + ((l >> 4) * 8) + 32]);
    }
    // CACHED: fold -QOFF into the row shift (decode adds u*QINV)
    const float nlr = -lrm_s[w*16 + (l & 15)] - (CACHED ? QOFF : 0.0f);

    // ones B-fragment: row n==0 of ones -> denominator column
    half8 ones8;
    {
        h16 ov = (h16)(((l & 15) == 0) ? 1.0f : 0.0f);
        #pragma unroll
        for (int e = 0; e < 8; ++e) ones8[e] = ov;
    }

    f32x4 pv[4];
    #pragma unroll
    for (int fd = 0; fd < 4; ++fd) pv[fd] = (f32x4){0.f,0.f,0.f,0.f};
    f32x4 pvden = (f32x4){0.f,0.f,0.f,0.f};

    // S addressing (CACHED): per (jc,fj) lane reads uint2 at l*4 u16 offset
    auto s_ptr = [&](int jc2, int fj) -> const uint2* {
        size_t sidx = (((((size_t)(bh*16 + jc2)*16 + it)*4 + w)*4 + fj) << 8) + (size_t)l*4;
        return reinterpret_cast<const uint2*>(&Sw[sidx]);
    };
    uint2 sv[4];
    if (CACHED) {
        #pragma unroll
        for (int fj = 0; fj < 4; ++fj) sv[fj] = *s_ptr(0, fj);
    }

    for (int jc = 0; jc < 16; ++jc) {
        const int j0 = jc * 64;
        __syncthreads();   // protect Ks/Vs reuse (Ps is wave-local)
        #pragma unroll
        for (int p = 0; p < 2; ++p) {
            int r = (t >> 3) + p * 32, c = (t & 7) * 8;
            if (!CACHED)
                *reinterpret_cast<half8*>(&Ks[r][c]) =
                    *reinterpret_cast<const half8*>(&kh[(((size_t)bh * SEQ) + j0 + r) * DHEAD + c]);
            *reinterpret_cast<half8*>(&Vs[r][c]) =
                *reinterpret_cast<const half8*>(&vt[(((size_t)bh * DHEAD) + r) * SEQ + j0 + c]);
        }
        if (t < 64) lcr_s[t] = lcr[(size_t)bh * SEQ + j0 + t];
        __syncthreads();

        // scores -> packed Ps writes
        #pragma unroll
        for (int fj = 0; fj < 4; ++fj) {
            float4 lc4 = *reinterpret_cast<const float4*>(&lcr_s[fj*16 + (l >> 4) * 4]);
            float pp0, pp1, pp2, pp3;
            if (CACHED) {
                float u0 = (float)(sv[fj].x & 0xffffu), u1 = (float)(sv[fj].x >> 16);
                float u2 = (float)(sv[fj].y & 0xffffu), u3 = (float)(sv[fj].y >> 16);
                pp0 = __builtin_amdgcn_exp2f(fmaf(u0, QINV, lc4.x + nlr));
                pp1 = __builtin_amdgcn_exp2f(fmaf(u1, QINV, lc4.y + nlr));
                pp2 = __builtin_amdgcn_exp2f(fmaf(u2, QINV, lc4.z + nlr));
                pp3 = __builtin_amdgcn_exp2f(fmaf(u3, QINV, lc4.w + nlr));
            } else {
                half8 kb0 = *reinterpret_cast<const half8*>(&Ks[fj*16 + (l & 15)][((l >> 4) * 8)]);
                half8 kb1 = *reinterpret_cast<const half8*>(&Ks[fj*16 + (l & 15)][((l >> 4) * 8) + 32]);
                f32x4 cfr = (f32x4){0.f,0.f,0.f,0.f};
                cfr = __builtin_amdgcn_mfma_f32_16x16x32_f16(kb0, aq0, cfr, 0, 0, 0);
                cfr = __builtin_amdgcn_mfma_f32_16x16x32_f16(kb1, aq1, cfr, 0, 0, 0);
                pp0 = __builtin_amdgcn_exp2f(fmaf(spfns_lg(cfr[0]), -PEXP, lc4.x + nlr));
                pp1 = __builtin_amdgcn_exp2f(fmaf(spfns_lg(cfr[1]), -PEXP, lc4.y + nlr));
                pp2 = __builtin_amdgcn_exp2f(fmaf(spfns_lg(cfr[2]), -PEXP, lc4.z + nlr));
                pp3 = __builtin_amdgcn_exp2f(fmaf(spfns_lg(cfr[3]), -PEXP, lc4.w + nlr));
            }
            uint2 pk;
            pk.x = pk_h2(pp0, pp1);
            pk.y = pk_h2(pp2, pp3);
            *reinterpret_cast<uint2*>(&Ps[w][l & 15][fj*16 + (l >> 4) * 4]) = pk;
        }
        // prefetch next chunk's S (overlaps PV + next stage)
        if (CACHED) {
            int jn = (jc < 15) ? jc + 1 : 15;
            #pragma unroll
            for (int fj = 0; fj < 4; ++fj) sv[fj] = *s_ptr(jn, fj);
        }
        // no barrier: Ps[w] is wave-local; same-wave DS ordering suffices

        // PV (+ denominator via ones column)
        half8 pa0 = *reinterpret_cast<const half8*>(&Ps[w][l & 15][((l >> 4) * 8)]);
        half8 pa1 = *reinterpret_cast<const half8*>(&Ps[w][l & 15][((l >> 4) * 8) + 32]);
        #pragma unroll
        for (int fd = 0; fd < 4; ++fd) {
            half8 vb0 = *reinterpret_cast<const half8*>(&Vs[fd*16 + (l & 15)][((l >> 4) * 8)]);
            half8 vb1 = *reinterpret_cast<const half8*>(&Vs[fd*16 + (l & 15)][((l >> 4) * 8) + 32]);
            pv[fd] = __builtin_amdgcn_mfma_f32_16x16x32_f16(pa0, vb0, pv[fd], 0, 0, 0);
            pv[fd] = __builtin_amdgcn_mfma_f32_16x16x32_f16(pa1, vb1, pv[fd], 0, 0, 0);
        }
        pvden = __builtin_amdgcn_mfma_f32_16x16x32_f16(pa0, ones8, pvden, 0, 0, 0);
        pvden = __builtin_amdgcn_mfma_f32_16x16x32_f16(pa1, ones8, pvden, 0, 0, 0);
    }

    // epilogue: denominator lives in lanes with (l&15)==0 of each 16-group
    const int b = bh >> 4, h = bh & 15;
    #pragma unroll
    for (int rr = 0; rr < 4; ++rr) {
        float ds = __shfl(pvden[rr], l & 48);
        float inv = __builtin_amdgcn_rcpf(ds);
        int s = i0 + w * 16 + ((l >> 4) << 2) + rr;
        #pragma unroll
        for (int fd = 0; fd < 4; ++fd) {
            aoh[((size_t)(b * SEQ + s)) * DMODEL + h * DHEAD + fd * 16 + (l & 15)] =
                (h16)(pv[fd][rr] * inv);
        }
    }
}

// ---------------------------------------------------------------------------
extern "C" void kernel_launch(void* const* d_in, const int* in_sizes, int n_in,
                              void* d_out, int out_size, void* d_ws, size_t ws_size,
                              hipStream_t stream)
{
    (void)in_sizes; (void)n_in; (void)out_size;
    const float* x  = (const float*)d_in[0];
    const float* wq = (const float*)d_in[1];
    const float* bq = (const float*)d_in[2];
    const float* wk = (const float*)d_in[3];
    const float* bk = (const float*)d_in[4];
    const float* wv = (const float*)d_in[5];
    const float* bv = (const float*)d_in[6];
    const float* wo = (const float*)d_in[7];
    const float* bo = (const float*)d_in[8];
    float* out = (float*)d_out;

    // workspace layout (halves first, then f32/u32, then optional S cache)
    h16* ws16 = (h16*)d_ws;
    const size_t NX  = (size_t)NROWS * DMODEL;      // 4,194,304
    const size_t NW3 = (size_t)3 * DMODEL * DMODEL; // 3,145,728
    const size_t NW1 = (size_t)DMODEL * DMODEL;     // 1,048,576
    const size_t NH  = (size_t)BH * SEQ * DHEAD;    // 4,194,304
    h16* xh  = ws16;
    h16* wt3 = xh  + NX;
    h16* wot = wt3 + NW3;
    h16* qh  = wot + NW1;
    h16* kh  = qh  + NH;      // contiguous after qh (l2norm covers both)
    h16* vt  = kh  + NH;
    h16* aoh = vt  + NH;
    float* nc  = (float*)(aoh + NX);
    float* lcr = nc  + BH * SEQ;
    float* lrm = lcr + BH * SEQ;
    unsigned* rm_u = (unsigned*)(lrm + BH * SEQ);
    int* gacc = (int*)(rm_u + BH * SEQ);

    size_t used = (size_t)((char*)(gacc + 1) - (char*)d_ws);
    used = (used + 255) & ~(size_t)255;
    unsigned short* Sw = (unsigned short*)((char*)d_ws + used);
    const size_t SBYTES = (size_t)BH * SEQ * SEQ * 2;   // 134,217,728
    const bool cache = (ws_size >= used + SBYTES);

    hipMemsetAsync(rm_u, 0xFF, (size_t)BH * SEQ * sizeof(unsigned), stream);
    hipMemsetAsync(gacc, 0, sizeof(int), stream);

    cvt_x<<<2048, 256, 0, stream>>>(x, xh);
    wtrans<<<dim3(16, 16, 4), 256, 0, stream>>>(wq, wk, wv, wo, wt3, wot);

    // q,k,v projections (d = 0..3071 over [wq|wk|wv])
    gemm_f16<<<dim3(32, 24), 256, 0, stream>>>(xh, wt3, bq, bk, bv,
                                               qh, kh, vt, nullptr, 0);
    l2norm_f16<<<(2 * BH * SEQ) / 16, 256, 0, stream>>>(qh);

    if (cache) {
        passA<1><<<dim3(16, BH), 256, 0, stream>>>(qh, kh, nc, rm_u, gacc, Sw);
        ncprep<<<256, 256, 0, stream>>>(nc, rm_u, gacc, lcr, lrm);
        passB<1><<<dim3(16, BH), 256, 0, stream>>>(qh, kh, vt, lcr, lrm, Sw, aoh);
    } else {
        passA<0><<<dim3(16, BH), 256, 0, stream>>>(qh, kh, nc, rm_u, gacc, Sw);
        ncprep<<<256, 256, 0, stream>>>(nc, rm_u, gacc, lcr, lrm);
        passB<0><<<dim3(16, BH), 256, 0, stream>>>(qh, kh, vt, lcr, lrm, Sw, aoh);
    }

    gemm_f16<<<dim3(32, 8), 256, 0, stream>>>(aoh, wot, bo, nullptr, nullptr,
                                              nullptr, nullptr, nullptr, out, 1);
}